// Round 1
// 1016.289 us; speedup vs baseline: 1.2068x; 1.2068x over previous
//
#include <hip/hip_runtime.h>

// Problem constants
#define Bn 4
#define Tn 2048
#define Cn 2048
#define Hn 32
#define Mn 8192              // B*T
#define EPSV 0.00064f
#define SEGS 8               // T-segments per (b,h) for the parallel scan

typedef __attribute__((ext_vector_type(8))) short short8;   // legacy
typedef __attribute__((ext_vector_type(4))) float f32x4;    // MFMA acc
typedef _Float16 half4 __attribute__((ext_vector_type(4)));
typedef _Float16 half8 __attribute__((ext_vector_type(8))); // 8 x f16 (4 VGPRs)

// ---------------- helpers ----------------
__device__ __forceinline__ unsigned short f2bf(float f) {   // round-to-nearest-even f32->bf16
  unsigned int u = __float_as_uint(f);
  u += 0x7fffu + ((u >> 16) & 1u);
  return (unsigned short)(u >> 16);
}
__device__ __forceinline__ float bf2f(unsigned short h) {
  return __uint_as_float(((unsigned int)h) << 16);
}

// ---------------- weight f32 -> f16 cast ----------------
// f16 (11-bit mantissa) weight error 2^-11 — below the f16 activation error,
// and 8x better than the old bf16 activation error this replaces.
__global__ __launch_bounds__(256) void wcast_f16_kernel(
    const float* __restrict__ src, _Float16* __restrict__ dst) {
  const size_t e = ((size_t)blockIdx.x * 256 + threadIdx.x) * 4;
  const float4 v = *(const float4*)(src + e);
  half4 h;
  h.x = (_Float16)v.x; h.y = (_Float16)v.y; h.z = (_Float16)v.z; h.w = (_Float16)v.w;
  *(half4*)(dst + e) = h;
}

// ---------------- token-shift mix (one slot) -> f16 activation matrix ----------------
__global__ __launch_bounds__(256) void mix_one_kernel(
    const float* __restrict__ x, const float* __restrict__ state,
    const float* __restrict__ tm, _Float16* __restrict__ xm) {
  const size_t e = ((size_t)blockIdx.x * 256 + threadIdx.x) * 4;
  const int c = (int)(e & (Cn - 1));
  const int t = (int)((e >> 11) & (Tn - 1));
  float4 xv  = *(const float4*)(x + e);
  float4 xxv = (t == 0) ? *(const float4*)(state + c) : *(const float4*)(x + e - Cn);
  float4 m = *(const float4*)(tm + c);
  half4 o;
  o.x = (_Float16)(xv.x * m.x + xxv.x * (1.f - m.x));
  o.y = (_Float16)(xv.y * m.y + xxv.y * (1.f - m.y));
  o.z = (_Float16)(xv.z * m.z + xxv.z * (1.f - m.z));
  o.w = (_Float16)(xv.w * m.w + xxv.w * (1.f - m.w));
  *(half4*)(xm + e) = o;
}

// ---------------- f16 GEMM, single pass: O = A @ W^T ----------------
// M = grid.y*128, N = grid.x*128, K=2048. 256 thr = 4 waves, wave = 64x64 subtile.
// OUT_F16=1 -> f16 output (projections), else f32 (final).
template <int OUT_F16>
__global__ __launch_bounds__(256) void gemm_f16_kernel(
    const _Float16* __restrict__ A, const _Float16* __restrict__ W,
    void* __restrict__ Ov) {
  __shared__ _Float16 As[128 * 32];  // 8 KB each; row r at byte r*64, XOR-swizzled 16B slots
  __shared__ _Float16 Bs[128 * 32];
  const int tid = threadIdx.x;
  const int wv = tid >> 6, ln = tid & 63;
  const int wm = wv >> 1, wn = wv & 1;
  const int m16 = ln & 15, qd = ln >> 4;

  const _Float16* Ab = A + (size_t)blockIdx.y * 128 * Cn;
  const _Float16* Wb = W + (size_t)blockIdx.x * 128 * Cn;

  // staging: per wave 2 insts/array; inst covers 1KB = 16 rows x 64B; lane L -> base + L*16
  const _Float16* gA[2]; const _Float16* gB[2];
  int lof[2];
#pragma unroll
  for (int tc = 0; tc < 2; ++tc) {
    int lo = ((wv * 2 + tc) << 10);            // LDS byte base (wave-uniform)
    int r  = (lo >> 6) + (ln >> 2);            // row this lane fills
    int q  = (ln & 3) ^ ((r >> 1) & 3);        // XOR swizzle: slot (ln&3) holds k-quad q
    gA[tc] = Ab + (size_t)r * Cn + (q << 3);
    gB[tc] = Wb + (size_t)r * Cn + (q << 3);
    lof[tc] = lo;
  }
  // fragment LDS byte offsets (constant across K)
  int aoff[4], boff[4];
#pragma unroll
  for (int mt = 0; mt < 4; ++mt) {
    int r = (wm << 6) + (mt << 4) + m16;
    aoff[mt] = (r << 6) + ((qd ^ ((r >> 1) & 3)) << 4);
  }
#pragma unroll
  for (int nt = 0; nt < 4; ++nt) {
    int r = (wn << 6) + (nt << 4) + m16;
    boff[nt] = (r << 6) + ((qd ^ ((r >> 1) & 3)) << 4);
  }

  f32x4 acc[4][4];
#pragma unroll
  for (int i = 0; i < 4; ++i)
#pragma unroll
    for (int j = 0; j < 4; ++j) acc[i][j] = 0.f;

  for (int k0 = 0; k0 < Cn; k0 += 32) {
#pragma unroll
    for (int tc = 0; tc < 2; ++tc) {
      __builtin_amdgcn_global_load_lds(
          (const __attribute__((address_space(1))) void*)(gA[tc] + k0),
          (__attribute__((address_space(3))) void*)((char*)As + lof[tc]), 16, 0, 0);
      __builtin_amdgcn_global_load_lds(
          (const __attribute__((address_space(1))) void*)(gB[tc] + k0),
          (__attribute__((address_space(3))) void*)((char*)Bs + lof[tc]), 16, 0, 0);
    }
    __syncthreads();
    half8 af[4], bfr[4];
#pragma unroll
    for (int mt = 0; mt < 4; ++mt) af[mt] = *(const half8*)((const char*)As + aoff[mt]);
#pragma unroll
    for (int nt = 0; nt < 4; ++nt) bfr[nt] = *(const half8*)((const char*)Bs + boff[nt]);
#pragma unroll
    for (int mt = 0; mt < 4; ++mt)
#pragma unroll
      for (int nt = 0; nt < 4; ++nt)
        acc[mt][nt] = __builtin_amdgcn_mfma_f32_16x16x32_f16(af[mt], bfr[nt], acc[mt][nt], 0, 0, 0);
    __syncthreads();
  }
  // epilogue: C/D layout col=lane&15, row=quad*4+reg (m89-verified)
#pragma unroll
  for (int mt = 0; mt < 4; ++mt) {
#pragma unroll
    for (int nt = 0; nt < 4; ++nt) {
      int col  = (wn << 6) + (nt << 4) + m16;
      int row0 = (wm << 6) + (mt << 4) + (qd << 2);
      f32x4 cv = acc[mt][nt];
      if constexpr (OUT_F16) {
        _Float16* Ob = (_Float16*)Ov + (size_t)blockIdx.y * 128 * Cn + (size_t)blockIdx.x * 128;
#pragma unroll
        for (int rg = 0; rg < 4; ++rg)
          Ob[(size_t)(row0 + rg) * Cn + col] = (_Float16)cv[rg];
      } else {
        float* Ob = (float*)Ov + (size_t)blockIdx.y * 128 * Cn + (size_t)blockIdx.x * 128;
#pragma unroll
        for (int rg = 0; rg < 4; ++rg)
          Ob[(size_t)(row0 + rg) * Cn + col] = cv[rg];
      }
    }
  }
}

// ---------------- scan pass 1: per-segment state sums ----------------
// segsum[bh][s] = sum over segment s of Kw^T V  (64x64 f32). S held in registers.
// grid (SEGS, 128). Chunks per segment = 64/SEGS.
__global__ __launch_bounds__(256) void seg_sum_kernel(
    const _Float16* __restrict__ kA, const _Float16* __restrict__ vA,
    const float* __restrict__ td, float* __restrict__ segsum) {
  __shared__ float sK[32][68];    // k * w^(T-1-t)
  __shared__ float sV[32][68];
  __shared__ float sEw[64];
  const int tid = threadIdx.x;
  const int seg = blockIdx.x;
  const int bh = blockIdx.y;
  const int b = bh >> 5, h = bh & 31;
  const size_t colbase = (size_t)b * Tn * Cn + h * 64;
  const _Float16* kG = kA + colbase;
  const _Float16* vG = vA + colbase;

  if (tid < 64) sEw[tid] = expf(td[h * 64 + tid]);
  __syncthreads();

  const int uk0 = (tid >> 4) << 2;      // S k base
  const int uj0 = (tid & 15) << 2;      // S j base
  float su[16];
#pragma unroll
  for (int i = 0; i < 16; ++i) su[i] = 0.f;

  const int c0 = seg * (64 / SEGS), c1 = c0 + (64 / SEGS);
  for (int c = c0; c < c1; ++c) {
    const int tb = c << 5;
#pragma unroll
    for (int rep = 0; rep < 2; ++rep) {
      int f4 = tid + (rep << 8);
      int row = f4 >> 4;
      int col = (f4 & 15) << 2;
      int t = tb + row;
      size_t off = (size_t)t * Cn + col;
      half4 ku = *(const half4*)(kG + off);
      half4 vu = *(const half4*)(vG + off);
      float4 vf; vf.x = (float)vu.x; vf.y = (float)vu.y; vf.z = (float)vu.z; vf.w = (float)vu.w;
      *(float4*)&sV[row][col] = vf;
      float e = (float)(Tn - 1 - t);
      float4 kw;
      kw.x = (float)ku.x * expf(-e * sEw[col + 0]);
      kw.y = (float)ku.y * expf(-e * sEw[col + 1]);
      kw.z = (float)ku.z * expf(-e * sEw[col + 2]);
      kw.w = (float)ku.w * expf(-e * sEw[col + 3]);
      *(float4*)&sK[row][col] = kw;
    }
    __syncthreads();
    for (int q = 0; q < 32; ++q) {
      float4 kq = *(const float4*)&sK[q][uk0];
      float4 vq = *(const float4*)&sV[q][uj0];
      su[0]  += kq.x * vq.x; su[1]  += kq.x * vq.y; su[2]  += kq.x * vq.z; su[3]  += kq.x * vq.w;
      su[4]  += kq.y * vq.x; su[5]  += kq.y * vq.y; su[6]  += kq.y * vq.z; su[7]  += kq.y * vq.w;
      su[8]  += kq.z * vq.x; su[9]  += kq.z * vq.y; su[10] += kq.z * vq.z; su[11] += kq.z * vq.w;
      su[12] += kq.w * vq.x; su[13] += kq.w * vq.y; su[14] += kq.w * vq.z; su[15] += kq.w * vq.w;
    }
    __syncthreads();
  }
  float* dst = segsum + ((size_t)bh * SEGS + seg) * 4096;
#pragma unroll
  for (int i = 0; i < 4; ++i) {
    float4 s; s.x = su[i * 4 + 0]; s.y = su[i * 4 + 1]; s.z = su[i * 4 + 2]; s.w = su[i * 4 + 3];
    *(float4*)(dst + (uk0 + i) * 64 + uj0) = s;
  }
}

// ---------------- scan pass 2: segmented WKV + folded base + fused GN*silu(g) ----------------
// out[t] = sum_{j<t} r_t . (k_j * w^(T-1-j)) v_j  +  (r_t * w^t) @ S0  +  (sum_k r_t k_t u_k) v_t
// grid (SEGS, 128): block handles 64/SEGS chunks of 32 rows; initial S = prefix of segsum.
__global__ __launch_bounds__(256) void scan_kernel(
    const _Float16* __restrict__ rA, const _Float16* __restrict__ kA,
    const _Float16* __restrict__ vA, const _Float16* __restrict__ gA,
    const float* __restrict__ wkvst, const float* __restrict__ td,
    const float* __restrict__ faaaa, const float* __restrict__ lnw,
    const float* __restrict__ lnb, const float* __restrict__ segsum,
    _Float16* __restrict__ A2) {
  __shared__ float sR[32][68];
  __shared__ float sK[32][68];    // k * w^(T-1-t)
  __shared__ float sV[32][68];
  __shared__ float sRW[32][68];   // r * w^t (only when chunk active)
  __shared__ float sS[64][68];
  __shared__ float sS0[64][68];
  __shared__ float sAtt[32][36];
  __shared__ float sEw[64];
  __shared__ float sU[64];
  __shared__ float sDotP[32][16];
  __shared__ float sRedM[32][8];
  __shared__ float sRedQ[32][8];
  __shared__ float sMV[32][2];
  __shared__ float sEwMin;
  const int tid = threadIdx.x;
  const int seg = blockIdx.x;
  const int bh = blockIdx.y;
  const int b = bh >> 5, h = bh & 31;
  const size_t colbase = (size_t)b * Tn * Cn + h * 64;
  const _Float16* rG = rA + colbase;
  const _Float16* kG = kA + colbase;
  const _Float16* vG = vA + colbase;
  const _Float16* gG = gA + colbase;
  _Float16* outG = A2 + colbase;

  if (tid < 64) {
    sEw[tid] = expf(td[h * 64 + tid]);
    sU[tid]  = faaaa[h * 64 + tid];
  }
  // ---- init sS = prefix sum of preceding segment sums; stage S0 ----
  {
    float4 acc4[4];
#pragma unroll
    for (int j = 0; j < 4; ++j) { acc4[j].x = 0.f; acc4[j].y = 0.f; acc4[j].z = 0.f; acc4[j].w = 0.f; }
    for (int sp = 0; sp < seg; ++sp) {
      const float* basep = segsum + ((size_t)bh * SEGS + sp) * 4096;
#pragma unroll
      for (int j = 0; j < 4; ++j) {
        int f4 = tid + j * 256;
        int row = f4 >> 4, c4 = (f4 & 15) << 2;
        float4 m = *(const float4*)(basep + row * 64 + c4);
        acc4[j].x += m.x; acc4[j].y += m.y; acc4[j].z += m.z; acc4[j].w += m.w;
      }
    }
#pragma unroll
    for (int j = 0; j < 4; ++j) {
      int f4 = tid + j * 256;
      int row = f4 >> 4, c4 = (f4 & 15) << 2;
      *(float4*)&sS[row][c4] = acc4[j];
      *(float4*)&sS0[row][c4] = *(const float4*)(wkvst + (size_t)h * 4096 + row * 64 + c4);
    }
  }
  __syncthreads();
  if (tid == 0) {
    float mn = sEw[0];
    for (int i = 1; i < 64; ++i) mn = fminf(mn, sEw[i]);
    sEwMin = mn;
  }
  __syncthreads();

  const int ap  = tid >> 3;             // att/out row (0..31)
  const int aq0 = (tid & 7) << 2;       // att col base
  const int oj0 = (tid & 7) << 3;       // out col base (8 cols)
  const int uk0 = (tid >> 4) << 2;      // S-update k base
  const int uj0 = (tid & 15) << 2;      // S-update j base
  float lw[8], lb[8];
#pragma unroll
  for (int i = 0; i < 8; ++i) { lw[i] = lnw[h * 64 + oj0 + i]; lb[i] = lnb[h * 64 + oj0 + i]; }

  const int c0 = seg * (64 / SEGS), c1 = c0 + (64 / SEGS);
  for (int c = c0; c < c1; ++c) {
    const int tb = c << 5;
    const bool active = ((float)tb * sEwMin) < 88.f;   // w^t underflows to 0 past this
    // ---- stage r, k*wback, v + u-dot partials + r*w^t (32 rows x 64 cols) ----
#pragma unroll
    for (int rep = 0; rep < 2; ++rep) {
      int f4 = tid + (rep << 8);
      int row = f4 >> 4;
      int col = (f4 & 15) << 2;
      int t = tb + row;
      size_t off = (size_t)t * Cn + col;
      half4 ru = *(const half4*)(rG + off);
      half4 ku = *(const half4*)(kG + off);
      half4 vu = *(const half4*)(vG + off);
      float4 rv; rv.x = (float)ru.x; rv.y = (float)ru.y; rv.z = (float)ru.z; rv.w = (float)ru.w;
      float4 kf; kf.x = (float)ku.x; kf.y = (float)ku.y; kf.z = (float)ku.z; kf.w = (float)ku.w;
      float4 vf; vf.x = (float)vu.x; vf.y = (float)vu.y; vf.z = (float)vu.z; vf.w = (float)vu.w;
      *(float4*)&sR[row][col] = rv;
      *(float4*)&sV[row][col] = vf;
      float e = (float)(Tn - 1 - t);
      float4 kw;
      kw.x = kf.x * expf(-e * sEw[col + 0]); kw.y = kf.y * expf(-e * sEw[col + 1]);
      kw.z = kf.z * expf(-e * sEw[col + 2]); kw.w = kf.w * expf(-e * sEw[col + 3]);
      *(float4*)&sK[row][col] = kw;
      sDotP[row][f4 & 15] =
          kf.x * rv.x * sU[col + 0] + kf.y * rv.y * sU[col + 1] +
          kf.z * rv.z * sU[col + 2] + kf.w * rv.w * sU[col + 3];
      if (active) {
        float tt = (float)t;
        float4 rw;
        rw.x = rv.x * expf(-tt * sEw[col + 0]); rw.y = rv.y * expf(-tt * sEw[col + 1]);
        rw.z = rv.z * expf(-tt * sEw[col + 2]); rw.w = rv.w * expf(-tt * sEw[col + 3]);
        *(float4*)&sRW[row][col] = rw;
      }
    }
    __syncthreads();
    // ---- att[p][q] = r_p . kw_q, strict mask q < p ----
    {
      float a[4] = {0.f, 0.f, 0.f, 0.f};
      for (int k = 0; k < 64; k += 4) {
        float4 rv = *(const float4*)&sR[ap][k];
#pragma unroll
        for (int qq = 0; qq < 4; ++qq) {
          float4 kv = *(const float4*)&sK[aq0 + qq][k];
          a[qq] += rv.x * kv.x + rv.y * kv.y + rv.z * kv.z + rv.w * kv.w;
        }
      }
#pragma unroll
      for (int qq = 0; qq < 4; ++qq)
        sAtt[ap][aq0 + qq] = ((aq0 + qq) < ap) ? a[qq] : 0.f;
    }
    __syncthreads();
    // ---- out = att@V + R@S (+ RW@S0) + dot*v; bf16-round; GN partials ----
    float y[8];
    {
      float o[8];
#pragma unroll
      for (int i = 0; i < 8; ++i) o[i] = 0.f;
      for (int q = 0; q < 32; ++q) {
        float aw = sAtt[ap][q];
        float4 v0 = *(const float4*)&sV[q][oj0];
        float4 v1 = *(const float4*)&sV[q][oj0 + 4];
        o[0] += aw * v0.x; o[1] += aw * v0.y; o[2] += aw * v0.z; o[3] += aw * v0.w;
        o[4] += aw * v1.x; o[5] += aw * v1.y; o[6] += aw * v1.z; o[7] += aw * v1.w;
      }
      for (int k = 0; k < 64; ++k) {
        float rw = sR[ap][k];
        float4 s0 = *(const float4*)&sS[k][oj0];
        float4 s1 = *(const float4*)&sS[k][oj0 + 4];
        o[0] += rw * s0.x; o[1] += rw * s0.y; o[2] += rw * s0.z; o[3] += rw * s0.w;
        o[4] += rw * s1.x; o[5] += rw * s1.y; o[6] += rw * s1.z; o[7] += rw * s1.w;
      }
      if (active) {
        for (int k = 0; k < 64; ++k) {
          float rw = sRW[ap][k];
          float4 s0 = *(const float4*)&sS0[k][oj0];
          float4 s1 = *(const float4*)&sS0[k][oj0 + 4];
          o[0] += rw * s0.x; o[1] += rw * s0.y; o[2] += rw * s0.z; o[3] += rw * s0.w;
          o[4] += rw * s1.x; o[5] += rw * s1.y; o[6] += rw * s1.z; o[7] += rw * s1.w;
        }
      }
      float dot = 0.f;
#pragma unroll
      for (int s = 0; s < 16; ++s) dot += sDotP[ap][s];
#pragma unroll
      for (int i = 0; i < 8; ++i) o[i] += dot * sV[ap][oj0 + i];
      float sm = 0.f, sq = 0.f;
#pragma unroll
      for (int i = 0; i < 8; ++i) {
        y[i] = bf2f(f2bf(o[i]));
        sm += y[i]; sq += y[i] * y[i];
      }
      sRedM[ap][tid & 7] = sm; sRedQ[ap][tid & 7] = sq;
    }
    __syncthreads();
    if ((tid & 7) == 0) {
      float sm = 0.f, sq = 0.f;
#pragma unroll
      for (int i = 0; i < 8; ++i) { sm += sRedM[ap][i]; sq += sRedQ[ap][i]; }
      float mu = sm * (1.f / 64.f);
      float var = sq * (1.f / 64.f) - mu * mu;
      sMV[ap][0] = mu; sMV[ap][1] = rsqrtf(var + EPSV);
    }
    __syncthreads();
    {
      float mu = sMV[ap][0], rs = sMV[ap][1];
      int t = tb + ap;
      size_t off = (size_t)t * Cn + oj0;
      half4 g0 = *(const half4*)(gG + off);
      half4 g1 = *(const half4*)(gG + off + 4);
      float gv[8] = {(float)g0.x, (float)g0.y, (float)g0.z, (float)g0.w,
                     (float)g1.x, (float)g1.y, (float)g1.z, (float)g1.w};
      _Float16 us[8];
#pragma unroll
      for (int i = 0; i < 8; ++i) {
        float yn = (y[i] - mu) * rs * lw[i] + lb[i];
        float gs = gv[i] / (1.f + expf(-gv[i]));
        us[i] = (_Float16)(yn * gs);
      }
      half4 o0, o1;
      o0.x = us[0]; o0.y = us[1]; o0.z = us[2]; o0.w = us[3];
      o1.x = us[4]; o1.y = us[5]; o1.z = us[6]; o1.w = us[7];
      *(half4*)(outG + off) = o0;
      *(half4*)(outG + off + 4) = o1;
    }
    // ---- S += Kw^T V (out-phase S reads fenced by the two GN barriers above) ----
    {
      float su[16];
#pragma unroll
      for (int i = 0; i < 4; ++i) {
        float4 s = *(const float4*)&sS[uk0 + i][uj0];
        su[i * 4 + 0] = s.x; su[i * 4 + 1] = s.y; su[i * 4 + 2] = s.z; su[i * 4 + 3] = s.w;
      }
      for (int q = 0; q < 32; ++q) {
        float4 kq = *(const float4*)&sK[q][uk0];
        float4 vq = *(const float4*)&sV[q][uj0];
        su[0]  += kq.x * vq.x; su[1]  += kq.x * vq.y; su[2]  += kq.x * vq.z; su[3]  += kq.x * vq.w;
        su[4]  += kq.y * vq.x; su[5]  += kq.y * vq.y; su[6]  += kq.y * vq.z; su[7]  += kq.y * vq.w;
        su[8]  += kq.z * vq.x; su[9]  += kq.z * vq.y; su[10] += kq.z * vq.z; su[11] += kq.z * vq.w;
        su[12] += kq.w * vq.x; su[13] += kq.w * vq.y; su[14] += kq.w * vq.z; su[15] += kq.w * vq.w;
      }
#pragma unroll
      for (int i = 0; i < 4; ++i) {
        float4 s; s.x = su[i * 4 + 0]; s.y = su[i * 4 + 1]; s.z = su[i * 4 + 2]; s.w = su[i * 4 + 3];
        *(float4*)&sS[uk0 + i][uj0] = s;
      }
    }
    __syncthreads();   // protect sR/sK/sV/sRW vs next staging, sS vs next out-phase
  }
}

// ---------------- launcher ----------------
extern "C" void kernel_launch(void* const* d_in, const int* in_sizes, int n_in,
                              void* d_out, int out_size, void* d_ws, size_t ws_size,
                              hipStream_t stream) {
  const float* x     = (const float*)d_in[0];
  const float* state = (const float*)d_in[1];
  const float* wkvst = (const float*)d_in[2];
  const float* tmk   = (const float*)d_in[3];
  const float* tmv   = (const float*)d_in[4];
  const float* tmr   = (const float*)d_in[5];
  const float* tmg   = (const float*)d_in[6];
  const float* td    = (const float*)d_in[7];
  const float* faaaa = (const float*)d_in[8];
  const float* w_r   = (const float*)d_in[9];
  const float* w_k   = (const float*)d_in[10];
  const float* w_v   = (const float*)d_in[11];
  const float* w_g   = (const float*)d_in[12];
  const float* w_o   = (const float*)d_in[13];
  const float* ln_w  = (const float*)d_in[14];
  const float* ln_b  = (const float*)d_in[15];
  float* out = (float*)d_out;
  char* ws = (char*)d_ws;

  // ws layout (bytes), peak ~192 MiB:
  //  [0, 8.4M)         weight f16 buffer (reused per GEMM)
  //  [16.8M, 50.3M)    xm f16 (reused per projection; later aliased by A2 f16)
  //  [50.3M, 184.5M)   r,k,v,g f16 (33.5M each)
  //  [184.5M, 201.3M)  segsum f32 (128 bh x 8 seg x 64 x 64)
  _Float16* wh  = (_Float16*)(ws);
  _Float16* xm  = (_Float16*)(ws + 16777216);
  _Float16* A2  = (_Float16*)(ws + 16777216);        // alias: xm dead after G-GEMM
  _Float16* proj = (_Float16*)(ws + 50331648);
  float* segsum  = (float*)(ws + 184549376);
  const size_t SLOT_E = (size_t)Mn * Cn;             // elems per activation matrix
  _Float16* R = proj;
  _Float16* K = proj + SLOT_E;
  _Float16* V = proj + 2 * SLOT_E;
  _Float16* G = proj + 3 * SLOT_E;

  const float* tms[4]  = {tmr, tmk, tmv, tmg};
  const float* wsrc[4] = {w_r, w_k, w_v, w_g};
  _Float16*    pdst[4] = {R, K, V, G};

  // per-projection pipeline (sequential stream order makes buffer reuse race-free)
  for (int s = 0; s < 4; ++s) {
    wcast_f16_kernel<<<dim3(4096), 256, 0, stream>>>(wsrc[s], wh);
    mix_one_kernel<<<dim3(16384), 256, 0, stream>>>(x, state, tms[s], xm);
    gemm_f16_kernel<1><<<dim3(16, 64), 256, 0, stream>>>(xm, wh, pdst[s]);
  }

  seg_sum_kernel<<<dim3(SEGS, 128), 256, 0, stream>>>(K, V, td, segsum);
  scan_kernel<<<dim3(SEGS, 128), 256, 0, stream>>>(R, K, V, G, wkvst, td, faaaa,
                                                   ln_w, ln_b, segsum, A2);

  wcast_f16_kernel<<<dim3(4096), 256, 0, stream>>>(w_o, wh);
  gemm_f16_kernel<0><<<dim3(16, 64), 256, 0, stream>>>(A2, wh, out);

  (void)in_sizes; (void)n_in; (void)out_size; (void)ws_size;
}

// Round 2
// 906.967 us; speedup vs baseline: 1.3522x; 1.1205x over previous
//
#include <hip/hip_runtime.h>

// Problem constants
#define Bn 4
#define Tn 2048
#define Cn 2048
#define Hn 32
#define Mn 8192              // B*T
#define EPSV 0.00064f
#define SEGS 8               // T-segments per (b,h) for the parallel scan
#define ZTHR 96.f            // (T-32-tb)*ewmin >= ZTHR  =>  whole chunk's kw underflows f32

typedef __attribute__((ext_vector_type(8))) short short8;   // legacy
typedef __attribute__((ext_vector_type(4))) float f32x4;    // MFMA acc
typedef _Float16 half4 __attribute__((ext_vector_type(4)));
typedef _Float16 half8 __attribute__((ext_vector_type(8))); // 8 x f16 (4 VGPRs)

// ---------------- helpers ----------------
__device__ __forceinline__ unsigned short f2bf(float f) {   // round-to-nearest-even f32->bf16
  unsigned int u = __float_as_uint(f);
  u += 0x7fffu + ((u >> 16) & 1u);
  return (unsigned short)(u >> 16);
}
__device__ __forceinline__ float bf2f(unsigned short h) {
  return __uint_as_float(((unsigned int)h) << 16);
}

// ---------------- weight f32 -> f16 cast ----------------
__global__ __launch_bounds__(256) void wcast_f16_kernel(
    const float* __restrict__ src, _Float16* __restrict__ dst) {
  const size_t e = ((size_t)blockIdx.x * 256 + threadIdx.x) * 4;
  const float4 v = *(const float4*)(src + e);
  half4 h;
  h.x = (_Float16)v.x; h.y = (_Float16)v.y; h.z = (_Float16)v.z; h.w = (_Float16)v.w;
  *(half4*)(dst + e) = h;
}

// ---------------- token-shift mix (one slot) -> f16 activation matrix ----------------
__global__ __launch_bounds__(256) void mix_one_kernel(
    const float* __restrict__ x, const float* __restrict__ state,
    const float* __restrict__ tm, _Float16* __restrict__ xm) {
  const size_t e = ((size_t)blockIdx.x * 256 + threadIdx.x) * 4;
  const int c = (int)(e & (Cn - 1));
  const int t = (int)((e >> 11) & (Tn - 1));
  float4 xv  = *(const float4*)(x + e);
  float4 xxv = (t == 0) ? *(const float4*)(state + c) : *(const float4*)(x + e - Cn);
  float4 m = *(const float4*)(tm + c);
  half4 o;
  o.x = (_Float16)(xv.x * m.x + xxv.x * (1.f - m.x));
  o.y = (_Float16)(xv.y * m.y + xxv.y * (1.f - m.y));
  o.z = (_Float16)(xv.z * m.z + xxv.z * (1.f - m.z));
  o.w = (_Float16)(xv.w * m.w + xxv.w * (1.f - m.w));
  *(half4*)(xm + e) = o;
}

// ---------------- f16 GEMM, single pass: O = A @ W^T ----------------
// M = grid.y*128, N = grid.x*128, K=2048. 256 thr = 4 waves, wave = 64x64 subtile.
template <int OUT_F16>
__global__ __launch_bounds__(256) void gemm_f16_kernel(
    const _Float16* __restrict__ A, const _Float16* __restrict__ W,
    void* __restrict__ Ov) {
  __shared__ _Float16 As[128 * 32];  // 8 KB each; row r at byte r*64, XOR-swizzled 16B slots
  __shared__ _Float16 Bs[128 * 32];
  const int tid = threadIdx.x;
  const int wv = tid >> 6, ln = tid & 63;
  const int wm = wv >> 1, wn = wv & 1;
  const int m16 = ln & 15, qd = ln >> 4;

  const _Float16* Ab = A + (size_t)blockIdx.y * 128 * Cn;
  const _Float16* Wb = W + (size_t)blockIdx.x * 128 * Cn;

  const _Float16* gA[2]; const _Float16* gB[2];
  int lof[2];
#pragma unroll
  for (int tc = 0; tc < 2; ++tc) {
    int lo = ((wv * 2 + tc) << 10);            // LDS byte base (wave-uniform)
    int r  = (lo >> 6) + (ln >> 2);            // row this lane fills
    int q  = (ln & 3) ^ ((r >> 1) & 3);        // XOR swizzle: slot (ln&3) holds k-quad q
    gA[tc] = Ab + (size_t)r * Cn + (q << 3);
    gB[tc] = Wb + (size_t)r * Cn + (q << 3);
    lof[tc] = lo;
  }
  int aoff[4], boff[4];
#pragma unroll
  for (int mt = 0; mt < 4; ++mt) {
    int r = (wm << 6) + (mt << 4) + m16;
    aoff[mt] = (r << 6) + ((qd ^ ((r >> 1) & 3)) << 4);
  }
#pragma unroll
  for (int nt = 0; nt < 4; ++nt) {
    int r = (wn << 6) + (nt << 4) + m16;
    boff[nt] = (r << 6) + ((qd ^ ((r >> 1) & 3)) << 4);
  }

  f32x4 acc[4][4];
#pragma unroll
  for (int i = 0; i < 4; ++i)
#pragma unroll
    for (int j = 0; j < 4; ++j) acc[i][j] = 0.f;

  for (int k0 = 0; k0 < Cn; k0 += 32) {
#pragma unroll
    for (int tc = 0; tc < 2; ++tc) {
      __builtin_amdgcn_global_load_lds(
          (const __attribute__((address_space(1))) void*)(gA[tc] + k0),
          (__attribute__((address_space(3))) void*)((char*)As + lof[tc]), 16, 0, 0);
      __builtin_amdgcn_global_load_lds(
          (const __attribute__((address_space(1))) void*)(gB[tc] + k0),
          (__attribute__((address_space(3))) void*)((char*)Bs + lof[tc]), 16, 0, 0);
    }
    __syncthreads();
    half8 af[4], bfr[4];
#pragma unroll
    for (int mt = 0; mt < 4; ++mt) af[mt] = *(const half8*)((const char*)As + aoff[mt]);
#pragma unroll
    for (int nt = 0; nt < 4; ++nt) bfr[nt] = *(const half8*)((const char*)Bs + boff[nt]);
#pragma unroll
    for (int mt = 0; mt < 4; ++mt)
#pragma unroll
      for (int nt = 0; nt < 4; ++nt)
        acc[mt][nt] = __builtin_amdgcn_mfma_f32_16x16x32_f16(af[mt], bfr[nt], acc[mt][nt], 0, 0, 0);
    __syncthreads();
  }
#pragma unroll
  for (int mt = 0; mt < 4; ++mt) {
#pragma unroll
    for (int nt = 0; nt < 4; ++nt) {
      int col  = (wn << 6) + (nt << 4) + m16;
      int row0 = (wm << 6) + (mt << 4) + (qd << 2);
      f32x4 cv = acc[mt][nt];
      if constexpr (OUT_F16) {
        _Float16* Ob = (_Float16*)Ov + (size_t)blockIdx.y * 128 * Cn + (size_t)blockIdx.x * 128;
#pragma unroll
        for (int rg = 0; rg < 4; ++rg)
          Ob[(size_t)(row0 + rg) * Cn + col] = (_Float16)cv[rg];
      } else {
        float* Ob = (float*)Ov + (size_t)blockIdx.y * 128 * Cn + (size_t)blockIdx.x * 128;
#pragma unroll
        for (int rg = 0; rg < 4; ++rg)
          Ob[(size_t)(row0 + rg) * Cn + col] = cv[rg];
      }
    }
  }
}

// ---------------- scan pass 1: per-segment state sums ----------------
// segsum[bh][s] = sum over segment s of Kw^T V  (64x64 f32).
// grid (128, SEGS): x = bh, y -> seg (reversed so heavy late segments dispatch first).
// Chunks whose kw fully underflows f32 (exactly as in the f32 reference) are skipped,
// including their HBM loads.
__global__ __launch_bounds__(256) void seg_sum_kernel(
    const _Float16* __restrict__ kA, const _Float16* __restrict__ vA,
    const float* __restrict__ td, float* __restrict__ segsum) {
  __shared__ float sK[32][68];    // k * w^(T-1-t)
  __shared__ float sV[32][68];
  __shared__ float sEw[64];
  __shared__ float sEwMin;
  const int tid = threadIdx.x;
  const int bh = blockIdx.x;
  const int seg = SEGS - 1 - blockIdx.y;
  const int b = bh >> 5, h = bh & 31;
  const size_t colbase = (size_t)b * Tn * Cn + h * 64;
  const _Float16* kG = kA + colbase;
  const _Float16* vG = vA + colbase;

  if (tid < 64) sEw[tid] = __expf(td[h * 64 + tid]);
  __syncthreads();
  if (tid == 0) {
    float mn = sEw[0];
    for (int i = 1; i < 64; ++i) mn = fminf(mn, sEw[i]);
    sEwMin = mn;
  }
  __syncthreads();

  const int uk0 = (tid >> 4) << 2;      // S k base
  const int uj0 = (tid & 15) << 2;      // S j base
  float su[16];
#pragma unroll
  for (int i = 0; i < 16; ++i) su[i] = 0.f;

  const int c0 = seg * (64 / SEGS), c1 = c0 + (64 / SEGS);
  for (int c = c0; c < c1; ++c) {
    const int tb = c << 5;
    // whole-chunk kw underflow: min exponent (T-32-tb)*ewmin >= ZTHR -> contribution == 0
    if ((float)(Tn - 32 - tb) * sEwMin >= ZTHR) continue;
#pragma unroll
    for (int rep = 0; rep < 2; ++rep) {
      int f4 = tid + (rep << 8);
      int row = f4 >> 4;
      int col = (f4 & 15) << 2;
      int t = tb + row;
      size_t off = (size_t)t * Cn + col;
      half4 ku = *(const half4*)(kG + off);
      half4 vu = *(const half4*)(vG + off);
      float4 vf; vf.x = (float)vu.x; vf.y = (float)vu.y; vf.z = (float)vu.z; vf.w = (float)vu.w;
      *(float4*)&sV[row][col] = vf;
      float e = (float)(Tn - 1 - t);
      float4 kw;
      kw.x = (float)ku.x * __expf(-e * sEw[col + 0]);
      kw.y = (float)ku.y * __expf(-e * sEw[col + 1]);
      kw.z = (float)ku.z * __expf(-e * sEw[col + 2]);
      kw.w = (float)ku.w * __expf(-e * sEw[col + 3]);
      *(float4*)&sK[row][col] = kw;
    }
    __syncthreads();
    for (int q = 0; q < 32; ++q) {
      float4 kq = *(const float4*)&sK[q][uk0];
      float4 vq = *(const float4*)&sV[q][uj0];
      su[0]  += kq.x * vq.x; su[1]  += kq.x * vq.y; su[2]  += kq.x * vq.z; su[3]  += kq.x * vq.w;
      su[4]  += kq.y * vq.x; su[5]  += kq.y * vq.y; su[6]  += kq.y * vq.z; su[7]  += kq.y * vq.w;
      su[8]  += kq.z * vq.x; su[9]  += kq.z * vq.y; su[10] += kq.z * vq.z; su[11] += kq.z * vq.w;
      su[12] += kq.w * vq.x; su[13] += kq.w * vq.y; su[14] += kq.w * vq.z; su[15] += kq.w * vq.w;
    }
    __syncthreads();
  }
  float* dst = segsum + ((size_t)bh * SEGS + seg) * 4096;
#pragma unroll
  for (int i = 0; i < 4; ++i) {
    float4 s; s.x = su[i * 4 + 0]; s.y = su[i * 4 + 1]; s.z = su[i * 4 + 2]; s.w = su[i * 4 + 3];
    *(float4*)(dst + (uk0 + i) * 64 + uj0) = s;
  }
}

// ---------------- scan pass 2: segmented WKV + folded base + fused GN*silu(g) ----------------
// grid (128, SEGS): x = bh, y -> seg (reversed, heavy-first).
// skipc <=> whole chunk's kw underflows f32 => att, att@V, S-update vanish.
// skipc is monotone (true for small tb) => S stays zero until first non-skipped chunk
// => R@S guarded by snz, and snz implies !skipc (so sR is always staged when needed).
__global__ __launch_bounds__(256) void scan_kernel(
    const _Float16* __restrict__ rA, const _Float16* __restrict__ kA,
    const _Float16* __restrict__ vA, const _Float16* __restrict__ gA,
    const float* __restrict__ wkvst, const float* __restrict__ td,
    const float* __restrict__ faaaa, const float* __restrict__ lnw,
    const float* __restrict__ lnb, const float* __restrict__ segsum,
    _Float16* __restrict__ A2) {
  __shared__ float sR[32][68];
  __shared__ float sK[32][68];    // k * w^(T-1-t)
  __shared__ float sV[32][68];
  __shared__ float sRW[32][68];   // r * w^t (only when chunk active)
  __shared__ float sS[64][68];
  __shared__ float sS0[64][68];
  __shared__ float sAtt[32][36];
  __shared__ float sEw[64];
  __shared__ float sU[64];
  __shared__ float sDotP[32][16];
  __shared__ float sRedM[32][8];
  __shared__ float sRedQ[32][8];
  __shared__ float sMV[32][2];
  __shared__ float sEwMin;
  const int tid = threadIdx.x;
  const int bh = blockIdx.x;
  const int seg = SEGS - 1 - blockIdx.y;
  const int b = bh >> 5, h = bh & 31;
  const size_t colbase = (size_t)b * Tn * Cn + h * 64;
  const _Float16* rG = rA + colbase;
  const _Float16* kG = kA + colbase;
  const _Float16* vG = vA + colbase;
  const _Float16* gG = gA + colbase;
  _Float16* outG = A2 + colbase;

  if (tid < 64) {
    sEw[tid] = __expf(td[h * 64 + tid]);
    sU[tid]  = faaaa[h * 64 + tid];
  }
  // ---- init sS = prefix sum of preceding segment sums; stage S0 ----
  {
    float4 acc4[4];
#pragma unroll
    for (int j = 0; j < 4; ++j) { acc4[j].x = 0.f; acc4[j].y = 0.f; acc4[j].z = 0.f; acc4[j].w = 0.f; }
    for (int sp = 0; sp < seg; ++sp) {
      const float* basep = segsum + ((size_t)bh * SEGS + sp) * 4096;
#pragma unroll
      for (int j = 0; j < 4; ++j) {
        int f4 = tid + j * 256;
        int row = f4 >> 4, c4 = (f4 & 15) << 2;
        float4 m = *(const float4*)(basep + row * 64 + c4);
        acc4[j].x += m.x; acc4[j].y += m.y; acc4[j].z += m.z; acc4[j].w += m.w;
      }
    }
#pragma unroll
    for (int j = 0; j < 4; ++j) {
      int f4 = tid + j * 256;
      int row = f4 >> 4, c4 = (f4 & 15) << 2;
      *(float4*)&sS[row][c4] = acc4[j];
      *(float4*)&sS0[row][c4] = *(const float4*)(wkvst + (size_t)h * 4096 + row * 64 + c4);
    }
  }
  __syncthreads();
  if (tid == 0) {
    float mn = sEw[0];
    for (int i = 1; i < 64; ++i) mn = fminf(mn, sEw[i]);
    sEwMin = mn;
  }
  __syncthreads();

  const int ap  = tid >> 3;             // att/out row (0..31)
  const int aq0 = (tid & 7) << 2;       // att col base
  const int oj0 = (tid & 7) << 3;       // out col base (8 cols)
  const int uk0 = (tid >> 4) << 2;      // S-update k base
  const int uj0 = (tid & 15) << 2;      // S-update j base
  float lw[8], lb[8];
#pragma unroll
  for (int i = 0; i < 8; ++i) { lw[i] = lnw[h * 64 + oj0 + i]; lb[i] = lnb[h * 64 + oj0 + i]; }

  // S nonzero iff some prefix chunk is non-skipped; last prefix chunk has
  // tb = seg*256-32  ->  (Tn-32-tb) = Tn - seg*256.
  bool snz = (seg > 0) && ((float)(Tn - seg * 256) * sEwMin < ZTHR);

  const int c0 = seg * (64 / SEGS), c1 = c0 + (64 / SEGS);
  for (int c = c0; c < c1; ++c) {
    const int tb = c << 5;
    const bool skipc  = ((float)(Tn - 32 - tb) * sEwMin) >= ZTHR;  // kw == 0 whole chunk
    const bool active = ((float)tb * sEwMin) < 88.f;               // w^t nonzero somewhere
    // ---- stage r, k*wback, v + u-dot partials + r*w^t (32 rows x 64 cols) ----
#pragma unroll
    for (int rep = 0; rep < 2; ++rep) {
      int f4 = tid + (rep << 8);
      int row = f4 >> 4;
      int col = (f4 & 15) << 2;
      int t = tb + row;
      size_t off = (size_t)t * Cn + col;
      half4 ru = *(const half4*)(rG + off);
      half4 ku = *(const half4*)(kG + off);
      half4 vu = *(const half4*)(vG + off);
      float4 rv; rv.x = (float)ru.x; rv.y = (float)ru.y; rv.z = (float)ru.z; rv.w = (float)ru.w;
      float4 kf; kf.x = (float)ku.x; kf.y = (float)ku.y; kf.z = (float)ku.z; kf.w = (float)ku.w;
      float4 vf; vf.x = (float)vu.x; vf.y = (float)vu.y; vf.z = (float)vu.z; vf.w = (float)vu.w;
      *(float4*)&sV[row][col] = vf;
      sDotP[row][f4 & 15] =
          kf.x * rv.x * sU[col + 0] + kf.y * rv.y * sU[col + 1] +
          kf.z * rv.z * sU[col + 2] + kf.w * rv.w * sU[col + 3];
      if (!skipc) {
        *(float4*)&sR[row][col] = rv;
        float e = (float)(Tn - 1 - t);
        float4 kw;
        kw.x = kf.x * __expf(-e * sEw[col + 0]); kw.y = kf.y * __expf(-e * sEw[col + 1]);
        kw.z = kf.z * __expf(-e * sEw[col + 2]); kw.w = kf.w * __expf(-e * sEw[col + 3]);
        *(float4*)&sK[row][col] = kw;
      }
      if (active) {
        float tt = (float)t;
        float4 rw;
        rw.x = rv.x * __expf(-tt * sEw[col + 0]); rw.y = rv.y * __expf(-tt * sEw[col + 1]);
        rw.z = rv.z * __expf(-tt * sEw[col + 2]); rw.w = rv.w * __expf(-tt * sEw[col + 3]);
        *(float4*)&sRW[row][col] = rw;
      }
    }
    __syncthreads();
    // ---- att[p][q] = r_p . kw_q, strict mask q < p (only when kw != 0) ----
    if (!skipc) {
      float a[4] = {0.f, 0.f, 0.f, 0.f};
      for (int k = 0; k < 64; k += 4) {
        float4 rv = *(const float4*)&sR[ap][k];
#pragma unroll
        for (int qq = 0; qq < 4; ++qq) {
          float4 kv = *(const float4*)&sK[aq0 + qq][k];
          a[qq] += rv.x * kv.x + rv.y * kv.y + rv.z * kv.z + rv.w * kv.w;
        }
      }
#pragma unroll
      for (int qq = 0; qq < 4; ++qq)
        sAtt[ap][aq0 + qq] = ((aq0 + qq) < ap) ? a[qq] : 0.f;
      __syncthreads();
    }
    // ---- out = [att@V] + [R@S] + [RW@S0] + dot*v; bf16-round; GN partials ----
    float y[8];
    {
      float o[8];
#pragma unroll
      for (int i = 0; i < 8; ++i) o[i] = 0.f;
      if (!skipc) {
        for (int q = 0; q < 32; ++q) {
          float aw = sAtt[ap][q];
          float4 v0 = *(const float4*)&sV[q][oj0];
          float4 v1 = *(const float4*)&sV[q][oj0 + 4];
          o[0] += aw * v0.x; o[1] += aw * v0.y; o[2] += aw * v0.z; o[3] += aw * v0.w;
          o[4] += aw * v1.x; o[5] += aw * v1.y; o[6] += aw * v1.z; o[7] += aw * v1.w;
        }
      }
      if (snz) {
        for (int k = 0; k < 64; ++k) {
          float rw = sR[ap][k];
          float4 s0 = *(const float4*)&sS[k][oj0];
          float4 s1 = *(const float4*)&sS[k][oj0 + 4];
          o[0] += rw * s0.x; o[1] += rw * s0.y; o[2] += rw * s0.z; o[3] += rw * s0.w;
          o[4] += rw * s1.x; o[5] += rw * s1.y; o[6] += rw * s1.z; o[7] += rw * s1.w;
        }
      }
      if (active) {
        for (int k = 0; k < 64; ++k) {
          float rw = sRW[ap][k];
          float4 s0 = *(const float4*)&sS0[k][oj0];
          float4 s1 = *(const float4*)&sS0[k][oj0 + 4];
          o[0] += rw * s0.x; o[1] += rw * s0.y; o[2] += rw * s0.z; o[3] += rw * s0.w;
          o[4] += rw * s1.x; o[5] += rw * s1.y; o[6] += rw * s1.z; o[7] += rw * s1.w;
        }
      }
      float dot = 0.f;
#pragma unroll
      for (int s = 0; s < 16; ++s) dot += sDotP[ap][s];
#pragma unroll
      for (int i = 0; i < 8; ++i) o[i] += dot * sV[ap][oj0 + i];
      float sm = 0.f, sq = 0.f;
#pragma unroll
      for (int i = 0; i < 8; ++i) {
        y[i] = bf2f(f2bf(o[i]));
        sm += y[i]; sq += y[i] * y[i];
      }
      sRedM[ap][tid & 7] = sm; sRedQ[ap][tid & 7] = sq;
    }
    __syncthreads();
    if ((tid & 7) == 0) {
      float sm = 0.f, sq = 0.f;
#pragma unroll
      for (int i = 0; i < 8; ++i) { sm += sRedM[ap][i]; sq += sRedQ[ap][i]; }
      float mu = sm * (1.f / 64.f);
      float var = sq * (1.f / 64.f) - mu * mu;
      sMV[ap][0] = mu; sMV[ap][1] = rsqrtf(var + EPSV);
    }
    __syncthreads();
    {
      float mu = sMV[ap][0], rs = sMV[ap][1];
      int t = tb + ap;
      size_t off = (size_t)t * Cn + oj0;
      half4 g0 = *(const half4*)(gG + off);
      half4 g1 = *(const half4*)(gG + off + 4);
      float gv[8] = {(float)g0.x, (float)g0.y, (float)g0.z, (float)g0.w,
                     (float)g1.x, (float)g1.y, (float)g1.z, (float)g1.w};
      _Float16 us[8];
#pragma unroll
      for (int i = 0; i < 8; ++i) {
        float yn = (y[i] - mu) * rs * lw[i] + lb[i];
        float gs = gv[i] / (1.f + __expf(-gv[i]));
        us[i] = (_Float16)(yn * gs);
      }
      half4 o0, o1;
      o0.x = us[0]; o0.y = us[1]; o0.z = us[2]; o0.w = us[3];
      o1.x = us[4]; o1.y = us[5]; o1.z = us[6]; o1.w = us[7];
      *(half4*)(outG + off) = o0;
      *(half4*)(outG + off + 4) = o1;
    }
    // ---- S += Kw^T V (skipc => Kw==0 => S unchanged; end barrier droppable then:
    // out-phase LDS reads are fenced by the GN barriers, and no LDS buffer written
    // by the next staging is read after them) ----
    if (!skipc) {
      float su[16];
#pragma unroll
      for (int i = 0; i < 4; ++i) {
        float4 s = *(const float4*)&sS[uk0 + i][uj0];
        su[i * 4 + 0] = s.x; su[i * 4 + 1] = s.y; su[i * 4 + 2] = s.z; su[i * 4 + 3] = s.w;
      }
      for (int q = 0; q < 32; ++q) {
        float4 kq = *(const float4*)&sK[q][uk0];
        float4 vq = *(const float4*)&sV[q][uj0];
        su[0]  += kq.x * vq.x; su[1]  += kq.x * vq.y; su[2]  += kq.x * vq.z; su[3]  += kq.x * vq.w;
        su[4]  += kq.y * vq.x; su[5]  += kq.y * vq.y; su[6]  += kq.y * vq.z; su[7]  += kq.y * vq.w;
        su[8]  += kq.z * vq.x; su[9]  += kq.z * vq.y; su[10] += kq.z * vq.z; su[11] += kq.z * vq.w;
        su[12] += kq.w * vq.x; su[13] += kq.w * vq.y; su[14] += kq.w * vq.z; su[15] += kq.w * vq.w;
      }
#pragma unroll
      for (int i = 0; i < 4; ++i) {
        float4 s; s.x = su[i * 4 + 0]; s.y = su[i * 4 + 1]; s.z = su[i * 4 + 2]; s.w = su[i * 4 + 3];
        *(float4*)&sS[uk0 + i][uj0] = s;
      }
      snz = true;
      __syncthreads();
    }
  }
}

// ---------------- launcher ----------------
extern "C" void kernel_launch(void* const* d_in, const int* in_sizes, int n_in,
                              void* d_out, int out_size, void* d_ws, size_t ws_size,
                              hipStream_t stream) {
  const float* x     = (const float*)d_in[0];
  const float* state = (const float*)d_in[1];
  const float* wkvst = (const float*)d_in[2];
  const float* tmk   = (const float*)d_in[3];
  const float* tmv   = (const float*)d_in[4];
  const float* tmr   = (const float*)d_in[5];
  const float* tmg   = (const float*)d_in[6];
  const float* td    = (const float*)d_in[7];
  const float* faaaa = (const float*)d_in[8];
  const float* w_r   = (const float*)d_in[9];
  const float* w_k   = (const float*)d_in[10];
  const float* w_v   = (const float*)d_in[11];
  const float* w_g   = (const float*)d_in[12];
  const float* w_o   = (const float*)d_in[13];
  const float* ln_w  = (const float*)d_in[14];
  const float* ln_b  = (const float*)d_in[15];
  float* out = (float*)d_out;
  char* ws = (char*)d_ws;

  // ws layout (bytes), peak ~192 MiB:
  //  [0, 8.4M)         weight f16 buffer (reused per GEMM)
  //  [16.8M, 50.3M)    xm f16 (reused per projection; later aliased by A2 f16)
  //  [50.3M, 184.5M)   r,k,v,g f16 (33.5M each)
  //  [184.5M, 201.3M)  segsum f32 (128 bh x 8 seg x 64 x 64)
  _Float16* wh  = (_Float16*)(ws);
  _Float16* xm  = (_Float16*)(ws + 16777216);
  _Float16* A2  = (_Float16*)(ws + 16777216);        // alias: xm dead after G-GEMM
  _Float16* proj = (_Float16*)(ws + 50331648);
  float* segsum  = (float*)(ws + 184549376);
  const size_t SLOT_E = (size_t)Mn * Cn;             // elems per activation matrix
  _Float16* R = proj;
  _Float16* K = proj + SLOT_E;
  _Float16* V = proj + 2 * SLOT_E;
  _Float16* G = proj + 3 * SLOT_E;

  const float* tms[4]  = {tmr, tmk, tmv, tmg};
  const float* wsrc[4] = {w_r, w_k, w_v, w_g};
  _Float16*    pdst[4] = {R, K, V, G};

  // per-projection pipeline (sequential stream order makes buffer reuse race-free)
  for (int s = 0; s < 4; ++s) {
    wcast_f16_kernel<<<dim3(4096), 256, 0, stream>>>(wsrc[s], wh);
    mix_one_kernel<<<dim3(16384), 256, 0, stream>>>(x, state, tms[s], xm);
    gemm_f16_kernel<1><<<dim3(16, 64), 256, 0, stream>>>(xm, wh, pdst[s]);
  }

  seg_sum_kernel<<<dim3(128, SEGS), 256, 0, stream>>>(K, V, td, segsum);
  scan_kernel<<<dim3(128, SEGS), 256, 0, stream>>>(R, K, V, G, wkvst, td, faaaa,
                                                   ln_w, ln_b, segsum, A2);

  wcast_f16_kernel<<<dim3(4096), 256, 0, stream>>>(w_o, wh);
  gemm_f16_kernel<0><<<dim3(16, 64), 256, 0, stream>>>(A2, wh, out);

  (void)in_sizes; (void)n_in; (void)out_size; (void)ws_size;
}

// Round 3
// 769.124 us; speedup vs baseline: 1.5946x; 1.1792x over previous
//
#include <hip/hip_runtime.h>

// Problem constants
#define Bn 4
#define Tn 2048
#define Cn 2048
#define Hn 32
#define Mn 8192              // B*T
#define EPSV 0.00064f
#define SEGS 8               // T-segments per (b,h) for the parallel scan
#define ZTHR 96.f            // (T-32-tb)*ewmin >= ZTHR  =>  whole chunk's kw underflows f32

typedef __attribute__((ext_vector_type(4))) float f32x4;    // MFMA acc
typedef _Float16 half4 __attribute__((ext_vector_type(4)));
typedef _Float16 half8 __attribute__((ext_vector_type(8))); // 8 x f16 (4 VGPRs)

// ---------------- helpers ----------------
__device__ __forceinline__ unsigned short f2bf(float f) {   // round-to-nearest-even f32->bf16
  unsigned int u = __float_as_uint(f);
  u += 0x7fffu + ((u >> 16) & 1u);
  return (unsigned short)(u >> 16);
}
__device__ __forceinline__ float bf2f(unsigned short h) {
  return __uint_as_float(((unsigned int)h) << 16);
}

// ---------------- weight f32 -> f16 cast ----------------
__global__ __launch_bounds__(256) void wcast_f16_kernel(
    const float* __restrict__ src, _Float16* __restrict__ dst) {
  const size_t e = ((size_t)blockIdx.x * 256 + threadIdx.x) * 4;
  const float4 v = *(const float4*)(src + e);
  half4 h;
  h.x = (_Float16)v.x; h.y = (_Float16)v.y; h.z = (_Float16)v.z; h.w = (_Float16)v.w;
  *(half4*)(dst + e) = h;
}

// ---------------- token-shift mix (one slot) -> f16 activation matrix ----------------
__global__ __launch_bounds__(256) void mix_one_kernel(
    const float* __restrict__ x, const float* __restrict__ state,
    const float* __restrict__ tm, _Float16* __restrict__ xm) {
  const size_t e = ((size_t)blockIdx.x * 256 + threadIdx.x) * 4;
  const int c = (int)(e & (Cn - 1));
  const int t = (int)((e >> 11) & (Tn - 1));
  float4 xv  = *(const float4*)(x + e);
  float4 xxv = (t == 0) ? *(const float4*)(state + c) : *(const float4*)(x + e - Cn);
  float4 m = *(const float4*)(tm + c);
  half4 o;
  o.x = (_Float16)(xv.x * m.x + xxv.x * (1.f - m.x));
  o.y = (_Float16)(xv.y * m.y + xxv.y * (1.f - m.y));
  o.z = (_Float16)(xv.z * m.z + xxv.z * (1.f - m.z));
  o.w = (_Float16)(xv.w * m.w + xxv.w * (1.f - m.w));
  *(half4*)(xm + e) = o;
}

// ---------------- f16 GEMM, 256x256 tile, BK=64, 8 waves, counted-vmcnt pipeline ----------
// O = A @ W^T. M = grid.y*256, N = grid.x*256, K = Cn.
// T2: LDS quad-swizzle byte ^= ((row&7)<<4), applied as inverse-swizzled global source
//     (linear global_load_lds dest) + swizzled ds_read (rule 21).
// T4: next K-tile's 8 loads issued BEFORE s_waitcnt vmcnt(8) -> stay in flight across
//     both barriers and the MFMA block; vmcnt never drains to 0 in the main loop.
// Race-freedom: end-of-tile barrier separates all ds_reads of buf b from the next
// iteration's stage writes into buf b; start barrier (after vmcnt(8)) guarantees every
// wave's tile-t loads have landed before any wave reads buf b.
template <int OUT_F16>
__global__ __launch_bounds__(512, 2) void gemm256_kernel(
    const _Float16* __restrict__ A, const _Float16* __restrict__ W,
    void* __restrict__ Ov) {
  __shared__ _Float16 As[2][256 * 64];   // 32 KB per buffer
  __shared__ _Float16 Bs[2][256 * 64];   // total 128 KB
  const int tid = threadIdx.x;
  const int wid = tid >> 6, ln = tid & 63;
  const int wm = wid >> 2, wn = wid & 3;          // 2 x 4 wave grid; wave owns 128x64 of C
  const int m16 = ln & 15, qd = ln >> 4;

  const int mtile = blockIdx.y, ntile = blockIdx.x;
  const _Float16* Ab = A + (size_t)mtile * 256 * Cn;
  const _Float16* Wb = W + (size_t)ntile * 256 * Cn;

  // staging: 4 insts per operand per wave; inst i covers LDS bytes [(wid*4+i)*1024,+1024)
  // lane L -> row r = (wid*4+i)*8 + (L>>3), slot s = L&7; source col-quad q = s ^ (r&7)
  const _Float16* gA[4]; const _Float16* gB[4];
  int lof[4];
#pragma unroll
  for (int i = 0; i < 4; ++i) {
    int r = ((wid * 4 + i) << 3) + (ln >> 3);
    int q = (ln & 7) ^ (r & 7);
    gA[i] = Ab + (size_t)r * Cn + (q << 3);
    gB[i] = Wb + (size_t)r * Cn + (q << 3);
    lof[i] = ((wid * 4 + i) << 10);               // wave-uniform LDS byte base
  }
  // fragment read offsets: row r = (sub-tile row) + m16, slot = ((h<<2)+qd) ^ (r&7);
  // r&7 == m16&7 since all other row terms are multiples of 8.
  int aob[2], bob[2];
#pragma unroll
  for (int h = 0; h < 2; ++h) {
    int sl = ((h << 2) + qd) ^ (m16 & 7);
    aob[h] = (wm * 128 + m16) * 128 + sl * 16;    // + fr*2048 per frag row
    bob[h] = (wn * 64 + m16) * 128 + sl * 16;     // + nf*2048 per frag col
  }

  f32x4 acc[8][4];
#pragma unroll
  for (int i = 0; i < 8; ++i)
#pragma unroll
    for (int j = 0; j < 4; ++j) acc[i][j] = 0.f;

  // prologue: stage K-tile 0 into buf 0
#pragma unroll
  for (int i = 0; i < 4; ++i) {
    __builtin_amdgcn_global_load_lds(
        (const __attribute__((address_space(1))) void*)(gA[i]),
        (__attribute__((address_space(3))) void*)((char*)&As[0][0] + lof[i]), 16, 0, 0);
    __builtin_amdgcn_global_load_lds(
        (const __attribute__((address_space(1))) void*)(gB[i]),
        (__attribute__((address_space(3))) void*)((char*)&Bs[0][0] + lof[i]), 16, 0, 0);
  }

  const int NT = Cn / 64;
  for (int t = 0; t < NT; ++t) {
    const int b = t & 1;
    if (t + 1 < NT) {
      const int k0 = (t + 1) << 6;
#pragma unroll
      for (int i = 0; i < 4; ++i) {
        __builtin_amdgcn_global_load_lds(
            (const __attribute__((address_space(1))) void*)(gA[i] + k0),
            (__attribute__((address_space(3))) void*)((char*)&As[b ^ 1][0] + lof[i]), 16, 0, 0);
        __builtin_amdgcn_global_load_lds(
            (const __attribute__((address_space(1))) void*)(gB[i] + k0),
            (__attribute__((address_space(3))) void*)((char*)&Bs[b ^ 1][0] + lof[i]), 16, 0, 0);
      }
      asm volatile("s_waitcnt vmcnt(8)" ::: "memory");   // tile-t loads done; 8 stay in flight
    } else {
      asm volatile("s_waitcnt vmcnt(0)" ::: "memory");
    }
    __builtin_amdgcn_s_barrier();

    const char* Abase = (const char*)&As[b][0];
    const char* Bbase = (const char*)&Bs[b][0];
    half8 bf[4][2];
#pragma unroll
    for (int nf = 0; nf < 4; ++nf)
#pragma unroll
      for (int h = 0; h < 2; ++h)
        bf[nf][h] = *(const half8*)(Bbase + nf * 2048 + bob[h]);
#pragma unroll
    for (int p = 0; p < 4; ++p) {
      half8 af[2][2];
#pragma unroll
      for (int sub = 0; sub < 2; ++sub)
#pragma unroll
        for (int h = 0; h < 2; ++h)
          af[sub][h] = *(const half8*)(Abase + (p * 2 + sub) * 2048 + aob[h]);
      __builtin_amdgcn_s_setprio(1);
#pragma unroll
      for (int sub = 0; sub < 2; ++sub)
#pragma unroll
        for (int nf = 0; nf < 4; ++nf) {
          acc[p * 2 + sub][nf] =
              __builtin_amdgcn_mfma_f32_16x16x32_f16(af[sub][0], bf[nf][0], acc[p * 2 + sub][nf], 0, 0, 0);
          acc[p * 2 + sub][nf] =
              __builtin_amdgcn_mfma_f32_16x16x32_f16(af[sub][1], bf[nf][1], acc[p * 2 + sub][nf], 0, 0, 0);
        }
      __builtin_amdgcn_s_setprio(0);
    }
    __builtin_amdgcn_s_barrier();   // all reads of buf b done before next iter stages into it
  }

  // epilogue: C/D layout col=lane&15, row=quad*4+reg (m89-verified, same as prior kernel)
  const size_t obase = (size_t)mtile * 256 * Cn + (size_t)ntile * 256;
#pragma unroll
  for (int fr = 0; fr < 8; ++fr) {
#pragma unroll
    for (int nf = 0; nf < 4; ++nf) {
      int col  = wn * 64 + nf * 16 + m16;
      int row0 = wm * 128 + fr * 16 + (qd << 2);
      f32x4 cv = acc[fr][nf];
      if constexpr (OUT_F16) {
        _Float16* Ob = (_Float16*)Ov + obase;
#pragma unroll
        for (int rg = 0; rg < 4; ++rg)
          Ob[(size_t)(row0 + rg) * Cn + col] = (_Float16)cv[rg];
      } else {
        float* Ob = (float*)Ov + obase;
#pragma unroll
        for (int rg = 0; rg < 4; ++rg)
          Ob[(size_t)(row0 + rg) * Cn + col] = cv[rg];
      }
    }
  }
}

// ---------------- scan pass 1: per-segment state sums ----------------
// segsum[bh][s] = sum over segment s of Kw^T V  (64x64 f32).
// grid (128, SEGS): x = bh, y -> seg (reversed so heavy late segments dispatch first).
__global__ __launch_bounds__(256) void seg_sum_kernel(
    const _Float16* __restrict__ kA, const _Float16* __restrict__ vA,
    const float* __restrict__ td, float* __restrict__ segsum) {
  __shared__ float sK[32][68];    // k * w^(T-1-t)
  __shared__ float sV[32][68];
  __shared__ float sEw[64];
  __shared__ float sEwMin;
  const int tid = threadIdx.x;
  const int bh = blockIdx.x;
  const int seg = SEGS - 1 - blockIdx.y;
  const int b = bh >> 5, h = bh & 31;
  const size_t colbase = (size_t)b * Tn * Cn + h * 64;
  const _Float16* kG = kA + colbase;
  const _Float16* vG = vA + colbase;

  if (tid < 64) sEw[tid] = __expf(td[h * 64 + tid]);
  __syncthreads();
  if (tid == 0) {
    float mn = sEw[0];
    for (int i = 1; i < 64; ++i) mn = fminf(mn, sEw[i]);
    sEwMin = mn;
  }
  __syncthreads();

  const int uk0 = (tid >> 4) << 2;      // S k base
  const int uj0 = (tid & 15) << 2;      // S j base
  float su[16];
#pragma unroll
  for (int i = 0; i < 16; ++i) su[i] = 0.f;

  const int c0 = seg * (64 / SEGS), c1 = c0 + (64 / SEGS);
  for (int c = c0; c < c1; ++c) {
    const int tb = c << 5;
    if ((float)(Tn - 32 - tb) * sEwMin >= ZTHR) continue;   // whole chunk underflows
#pragma unroll
    for (int rep = 0; rep < 2; ++rep) {
      int f4 = tid + (rep << 8);
      int row = f4 >> 4;
      int col = (f4 & 15) << 2;
      int t = tb + row;
      size_t off = (size_t)t * Cn + col;
      half4 ku = *(const half4*)(kG + off);
      half4 vu = *(const half4*)(vG + off);
      float4 vf; vf.x = (float)vu.x; vf.y = (float)vu.y; vf.z = (float)vu.z; vf.w = (float)vu.w;
      *(float4*)&sV[row][col] = vf;
      float e = (float)(Tn - 1 - t);
      float4 kw;
      kw.x = (float)ku.x * __expf(-e * sEw[col + 0]);
      kw.y = (float)ku.y * __expf(-e * sEw[col + 1]);
      kw.z = (float)ku.z * __expf(-e * sEw[col + 2]);
      kw.w = (float)ku.w * __expf(-e * sEw[col + 3]);
      *(float4*)&sK[row][col] = kw;
    }
    __syncthreads();
    for (int q = 0; q < 32; ++q) {
      float4 kq = *(const float4*)&sK[q][uk0];
      float4 vq = *(const float4*)&sV[q][uj0];
      su[0]  += kq.x * vq.x; su[1]  += kq.x * vq.y; su[2]  += kq.x * vq.z; su[3]  += kq.x * vq.w;
      su[4]  += kq.y * vq.x; su[5]  += kq.y * vq.y; su[6]  += kq.y * vq.z; su[7]  += kq.y * vq.w;
      su[8]  += kq.z * vq.x; su[9]  += kq.z * vq.y; su[10] += kq.z * vq.z; su[11] += kq.z * vq.w;
      su[12] += kq.w * vq.x; su[13] += kq.w * vq.y; su[14] += kq.w * vq.z; su[15] += kq.w * vq.w;
    }
    __syncthreads();
  }
  float* dst = segsum + ((size_t)bh * SEGS + seg) * 4096;
#pragma unroll
  for (int i = 0; i < 4; ++i) {
    float4 s; s.x = su[i * 4 + 0]; s.y = su[i * 4 + 1]; s.z = su[i * 4 + 2]; s.w = su[i * 4 + 3];
    *(float4*)(dst + (uk0 + i) * 64 + uj0) = s;
  }
}

// ---------------- scan pass 2: segmented WKV + folded base + fused GN*silu(g) ----------------
__global__ __launch_bounds__(256) void scan_kernel(
    const _Float16* __restrict__ rA, const _Float16* __restrict__ kA,
    const _Float16* __restrict__ vA, const _Float16* __restrict__ gA,
    const float* __restrict__ wkvst, const float* __restrict__ td,
    const float* __restrict__ faaaa, const float* __restrict__ lnw,
    const float* __restrict__ lnb, const float* __restrict__ segsum,
    _Float16* __restrict__ A2) {
  __shared__ float sR[32][68];
  __shared__ float sK[32][68];    // k * w^(T-1-t)
  __shared__ float sV[32][68];
  __shared__ float sRW[32][68];   // r * w^t (only when chunk active)
  __shared__ float sS[64][68];
  __shared__ float sS0[64][68];
  __shared__ float sAtt[32][36];
  __shared__ float sEw[64];
  __shared__ float sU[64];
  __shared__ float sDotP[32][16];
  __shared__ float sRedM[32][8];
  __shared__ float sRedQ[32][8];
  __shared__ float sMV[32][2];
  __shared__ float sEwMin;
  const int tid = threadIdx.x;
  const int bh = blockIdx.x;
  const int seg = SEGS - 1 - blockIdx.y;
  const int b = bh >> 5, h = bh & 31;
  const size_t colbase = (size_t)b * Tn * Cn + h * 64;
  const _Float16* rG = rA + colbase;
  const _Float16* kG = kA + colbase;
  const _Float16* vG = vA + colbase;
  const _Float16* gG = gA + colbase;
  _Float16* outG = A2 + colbase;

  if (tid < 64) {
    sEw[tid] = __expf(td[h * 64 + tid]);
    sU[tid]  = faaaa[h * 64 + tid];
  }
  // ---- init sS = prefix sum of preceding segment sums; stage S0 ----
  {
    float4 acc4[4];
#pragma unroll
    for (int j = 0; j < 4; ++j) { acc4[j].x = 0.f; acc4[j].y = 0.f; acc4[j].z = 0.f; acc4[j].w = 0.f; }
    for (int sp = 0; sp < seg; ++sp) {
      const float* basep = segsum + ((size_t)bh * SEGS + sp) * 4096;
#pragma unroll
      for (int j = 0; j < 4; ++j) {
        int f4 = tid + j * 256;
        int row = f4 >> 4, c4 = (f4 & 15) << 2;
        float4 m = *(const float4*)(basep + row * 64 + c4);
        acc4[j].x += m.x; acc4[j].y += m.y; acc4[j].z += m.z; acc4[j].w += m.w;
      }
    }
#pragma unroll
    for (int j = 0; j < 4; ++j) {
      int f4 = tid + j * 256;
      int row = f4 >> 4, c4 = (f4 & 15) << 2;
      *(float4*)&sS[row][c4] = acc4[j];
      *(float4*)&sS0[row][c4] = *(const float4*)(wkvst + (size_t)h * 4096 + row * 64 + c4);
    }
  }
  __syncthreads();
  if (tid == 0) {
    float mn = sEw[0];
    for (int i = 1; i < 64; ++i) mn = fminf(mn, sEw[i]);
    sEwMin = mn;
  }
  __syncthreads();

  const int ap  = tid >> 3;             // att/out row (0..31)
  const int aq0 = (tid & 7) << 2;       // att col base
  const int oj0 = (tid & 7) << 3;       // out col base (8 cols)
  const int uk0 = (tid >> 4) << 2;      // S-update k base
  const int uj0 = (tid & 15) << 2;      // S-update j base
  float lw[8], lb[8];
#pragma unroll
  for (int i = 0; i < 8; ++i) { lw[i] = lnw[h * 64 + oj0 + i]; lb[i] = lnb[h * 64 + oj0 + i]; }

  bool snz = (seg > 0) && ((float)(Tn - seg * 256) * sEwMin < ZTHR);

  const int c0 = seg * (64 / SEGS), c1 = c0 + (64 / SEGS);
  for (int c = c0; c < c1; ++c) {
    const int tb = c << 5;
    const bool skipc  = ((float)(Tn - 32 - tb) * sEwMin) >= ZTHR;  // kw == 0 whole chunk
    const bool active = ((float)tb * sEwMin) < 88.f;               // w^t nonzero somewhere
#pragma unroll
    for (int rep = 0; rep < 2; ++rep) {
      int f4 = tid + (rep << 8);
      int row = f4 >> 4;
      int col = (f4 & 15) << 2;
      int t = tb + row;
      size_t off = (size_t)t * Cn + col;
      half4 ru = *(const half4*)(rG + off);
      half4 ku = *(const half4*)(kG + off);
      half4 vu = *(const half4*)(vG + off);
      float4 rv; rv.x = (float)ru.x; rv.y = (float)ru.y; rv.z = (float)ru.z; rv.w = (float)ru.w;
      float4 kf; kf.x = (float)ku.x; kf.y = (float)ku.y; kf.z = (float)ku.z; kf.w = (float)ku.w;
      float4 vf; vf.x = (float)vu.x; vf.y = (float)vu.y; vf.z = (float)vu.z; vf.w = (float)vu.w;
      *(float4*)&sV[row][col] = vf;
      sDotP[row][f4 & 15] =
          kf.x * rv.x * sU[col + 0] + kf.y * rv.y * sU[col + 1] +
          kf.z * rv.z * sU[col + 2] + kf.w * rv.w * sU[col + 3];
      if (!skipc) {
        *(float4*)&sR[row][col] = rv;
        float e = (float)(Tn - 1 - t);
        float4 kw;
        kw.x = kf.x * __expf(-e * sEw[col + 0]); kw.y = kf.y * __expf(-e * sEw[col + 1]);
        kw.z = kf.z * __expf(-e * sEw[col + 2]); kw.w = kf.w * __expf(-e * sEw[col + 3]);
        *(float4*)&sK[row][col] = kw;
      }
      if (active) {
        float tt = (float)t;
        float4 rw;
        rw.x = rv.x * __expf(-tt * sEw[col + 0]); rw.y = rv.y * __expf(-tt * sEw[col + 1]);
        rw.z = rv.z * __expf(-tt * sEw[col + 2]); rw.w = rv.w * __expf(-tt * sEw[col + 3]);
        *(float4*)&sRW[row][col] = rw;
      }
    }
    __syncthreads();
    if (!skipc) {
      float a[4] = {0.f, 0.f, 0.f, 0.f};
      for (int k = 0; k < 64; k += 4) {
        float4 rv = *(const float4*)&sR[ap][k];
#pragma unroll
        for (int qq = 0; qq < 4; ++qq) {
          float4 kv = *(const float4*)&sK[aq0 + qq][k];
          a[qq] += rv.x * kv.x + rv.y * kv.y + rv.z * kv.z + rv.w * kv.w;
        }
      }
#pragma unroll
      for (int qq = 0; qq < 4; ++qq)
        sAtt[ap][aq0 + qq] = ((aq0 + qq) < ap) ? a[qq] : 0.f;
      __syncthreads();
    }
    float y[8];
    {
      float o[8];
#pragma unroll
      for (int i = 0; i < 8; ++i) o[i] = 0.f;
      if (!skipc) {
        for (int q = 0; q < 32; ++q) {
          float aw = sAtt[ap][q];
          float4 v0 = *(const float4*)&sV[q][oj0];
          float4 v1 = *(const float4*)&sV[q][oj0 + 4];
          o[0] += aw * v0.x; o[1] += aw * v0.y; o[2] += aw * v0.z; o[3] += aw * v0.w;
          o[4] += aw * v1.x; o[5] += aw * v1.y; o[6] += aw * v1.z; o[7] += aw * v1.w;
        }
      }
      if (snz) {
        for (int k = 0; k < 64; ++k) {
          float rw = sR[ap][k];
          float4 s0 = *(const float4*)&sS[k][oj0];
          float4 s1 = *(const float4*)&sS[k][oj0 + 4];
          o[0] += rw * s0.x; o[1] += rw * s0.y; o[2] += rw * s0.z; o[3] += rw * s0.w;
          o[4] += rw * s1.x; o[5] += rw * s1.y; o[6] += rw * s1.z; o[7] += rw * s1.w;
        }
      }
      if (active) {
        for (int k = 0; k < 64; ++k) {
          float rw = sRW[ap][k];
          float4 s0 = *(const float4*)&sS0[k][oj0];
          float4 s1 = *(const float4*)&sS0[k][oj0 + 4];
          o[0] += rw * s0.x; o[1] += rw * s0.y; o[2] += rw * s0.z; o[3] += rw * s0.w;
          o[4] += rw * s1.x; o[5] += rw * s1.y; o[6] += rw * s1.z; o[7] += rw * s1.w;
        }
      }
      float dot = 0.f;
#pragma unroll
      for (int s = 0; s < 16; ++s) dot += sDotP[ap][s];
#pragma unroll
      for (int i = 0; i < 8; ++i) o[i] += dot * sV[ap][oj0 + i];
      float sm = 0.f, sq = 0.f;
#pragma unroll
      for (int i = 0; i < 8; ++i) {
        y[i] = bf2f(f2bf(o[i]));
        sm += y[i]; sq += y[i] * y[i];
      }
      sRedM[ap][tid & 7] = sm; sRedQ[ap][tid & 7] = sq;
    }
    __syncthreads();
    if ((tid & 7) == 0) {
      float sm = 0.f, sq = 0.f;
#pragma unroll
      for (int i = 0; i < 8; ++i) { sm += sRedM[ap][i]; sq += sRedQ[ap][i]; }
      float mu = sm * (1.f / 64.f);
      float var = sq * (1.f / 64.f) - mu * mu;
      sMV[ap][0] = mu; sMV[ap][1] = rsqrtf(var + EPSV);
    }
    __syncthreads();
    {
      float mu = sMV[ap][0], rs = sMV[ap][1];
      int t = tb + ap;
      size_t off = (size_t)t * Cn + oj0;
      half4 g0 = *(const half4*)(gG + off);
      half4 g1 = *(const half4*)(gG + off + 4);
      float gv[8] = {(float)g0.x, (float)g0.y, (float)g0.z, (float)g0.w,
                     (float)g1.x, (float)g1.y, (float)g1.z, (float)g1.w};
      _Float16 us[8];
#pragma unroll
      for (int i = 0; i < 8; ++i) {
        float yn = (y[i] - mu) * rs * lw[i] + lb[i];
        float gs = gv[i] / (1.f + __expf(-gv[i]));
        us[i] = (_Float16)(yn * gs);
      }
      half4 o0, o1;
      o0.x = us[0]; o0.y = us[1]; o0.z = us[2]; o0.w = us[3];
      o1.x = us[4]; o1.y = us[5]; o1.z = us[6]; o1.w = us[7];
      *(half4*)(outG + off) = o0;
      *(half4*)(outG + off + 4) = o1;
    }
    if (!skipc) {
      float su[16];
#pragma unroll
      for (int i = 0; i < 4; ++i) {
        float4 s = *(const float4*)&sS[uk0 + i][uj0];
        su[i * 4 + 0] = s.x; su[i * 4 + 1] = s.y; su[i * 4 + 2] = s.z; su[i * 4 + 3] = s.w;
      }
      for (int q = 0; q < 32; ++q) {
        float4 kq = *(const float4*)&sK[q][uk0];
        float4 vq = *(const float4*)&sV[q][uj0];
        su[0]  += kq.x * vq.x; su[1]  += kq.x * vq.y; su[2]  += kq.x * vq.z; su[3]  += kq.x * vq.w;
        su[4]  += kq.y * vq.x; su[5]  += kq.y * vq.y; su[6]  += kq.y * vq.z; su[7]  += kq.y * vq.w;
        su[8]  += kq.z * vq.x; su[9]  += kq.z * vq.y; su[10] += kq.z * vq.z; su[11] += kq.z * vq.w;
        su[12] += kq.w * vq.x; su[13] += kq.w * vq.y; su[14] += kq.w * vq.z; su[15] += kq.w * vq.w;
      }
#pragma unroll
      for (int i = 0; i < 4; ++i) {
        float4 s; s.x = su[i * 4 + 0]; s.y = su[i * 4 + 1]; s.z = su[i * 4 + 2]; s.w = su[i * 4 + 3];
        *(float4*)&sS[uk0 + i][uj0] = s;
      }
      snz = true;
      __syncthreads();
    }
  }
}

// ---------------- launcher ----------------
extern "C" void kernel_launch(void* const* d_in, const int* in_sizes, int n_in,
                              void* d_out, int out_size, void* d_ws, size_t ws_size,
                              hipStream_t stream) {
  const float* x     = (const float*)d_in[0];
  const float* state = (const float*)d_in[1];
  const float* wkvst = (const float*)d_in[2];
  const float* tmk   = (const float*)d_in[3];
  const float* tmv   = (const float*)d_in[4];
  const float* tmr   = (const float*)d_in[5];
  const float* tmg   = (const float*)d_in[6];
  const float* td    = (const float*)d_in[7];
  const float* faaaa = (const float*)d_in[8];
  const float* w_r   = (const float*)d_in[9];
  const float* w_k   = (const float*)d_in[10];
  const float* w_v   = (const float*)d_in[11];
  const float* w_g   = (const float*)d_in[12];
  const float* w_o   = (const float*)d_in[13];
  const float* ln_w  = (const float*)d_in[14];
  const float* ln_b  = (const float*)d_in[15];
  float* out = (float*)d_out;
  char* ws = (char*)d_ws;

  // ws layout (bytes), peak ~201 MiB:
  //  [0, 8.4M)         weight f16 buffer (reused per GEMM)
  //  [16.8M, 50.3M)    xm f16 (reused per projection; later aliased by A2 f16)
  //  [50.3M, 184.5M)   r,k,v,g f16 (33.5M each)
  //  [184.5M, 201.3M)  segsum f32 (128 bh x 8 seg x 64 x 64)
  _Float16* wh  = (_Float16*)(ws);
  _Float16* xm  = (_Float16*)(ws + 16777216);
  _Float16* A2  = (_Float16*)(ws + 16777216);        // alias: xm dead after G-GEMM
  _Float16* proj = (_Float16*)(ws + 50331648);
  float* segsum  = (float*)(ws + 184549376);
  const size_t SLOT_E = (size_t)Mn * Cn;             // elems per activation matrix
  _Float16* R = proj;
  _Float16* K = proj + SLOT_E;
  _Float16* V = proj + 2 * SLOT_E;
  _Float16* G = proj + 3 * SLOT_E;

  const float* tms[4]  = {tmr, tmk, tmv, tmg};
  const float* wsrc[4] = {w_r, w_k, w_v, w_g};
  _Float16*    pdst[4] = {R, K, V, G};

  // per-projection pipeline (sequential stream order makes buffer reuse race-free)
  for (int s = 0; s < 4; ++s) {
    wcast_f16_kernel<<<dim3(4096), 256, 0, stream>>>(wsrc[s], wh);
    mix_one_kernel<<<dim3(16384), 256, 0, stream>>>(x, state, tms[s], xm);
    gemm256_kernel<1><<<dim3(Cn / 256, Mn / 256), 512, 0, stream>>>(xm, wh, pdst[s]);
  }

  seg_sum_kernel<<<dim3(128, SEGS), 256, 0, stream>>>(K, V, td, segsum);
  scan_kernel<<<dim3(128, SEGS), 256, 0, stream>>>(R, K, V, G, wkvst, td, faaaa,
                                                   ln_w, ln_b, segsum, A2);

  wcast_f16_kernel<<<dim3(4096), 256, 0, stream>>>(w_o, wh);
  gemm256_kernel<0><<<dim3(Cn / 256, Mn / 256), 512, 0, stream>>>(A2, wh, out);

  (void)in_sizes; (void)n_in; (void)out_size; (void)ws_size;
}

// Round 4
// 730.254 us; speedup vs baseline: 1.6795x; 1.0532x over previous
//
#include <hip/hip_runtime.h>

// Problem constants
#define Bn 4
#define Tn 2048
#define Cn 2048
#define Hn 32
#define Mn 8192              // B*T
#define EPSV 0.00064f
#define SEGS 8               // T-segments per (b,h) for the parallel scan
#define ZTHR 96.f            // (T-32-tb)*ewmin >= ZTHR  =>  whole chunk's kw underflows f32

typedef __attribute__((ext_vector_type(4))) float f32x4;    // MFMA acc
typedef _Float16 half4 __attribute__((ext_vector_type(4)));
typedef _Float16 half8 __attribute__((ext_vector_type(8))); // 8 x f16 (4 VGPRs)
typedef _Float16 h2 __attribute__((ext_vector_type(2)));

#if defined(__has_builtin)
#if __has_builtin(__builtin_amdgcn_fdot2)
#define HAS_FDOT2 1
#endif
#endif
#ifndef HAS_FDOT2
#define HAS_FDOT2 0
#endif

// XOR col-block swizzle for f16 LDS tiles: spreads 4-row-strided accesses across banks.
// Bijective per row; affects col bits 3..5 only (safe for 4-aligned half4 sub-access).
#define SWZ(row, col) ((col) ^ ((((row) >> 2) & 7) << 3))

// ---------------- helpers ----------------
__device__ __forceinline__ unsigned short f2bf(float f) {   // round-to-nearest-even f32->bf16
  unsigned int u = __float_as_uint(f);
  u += 0x7fffu + ((u >> 16) & 1u);
  return (unsigned short)(u >> 16);
}
__device__ __forceinline__ float bf2f(unsigned short h) {
  return __uint_as_float(((unsigned int)h) << 16);
}

__device__ __forceinline__ float dot8(half8 a, half8 b, float acc) {
#if HAS_FDOT2
  acc = __builtin_amdgcn_fdot2(__builtin_shufflevector(a, a, 0, 1),
                               __builtin_shufflevector(b, b, 0, 1), acc, false);
  acc = __builtin_amdgcn_fdot2(__builtin_shufflevector(a, a, 2, 3),
                               __builtin_shufflevector(b, b, 2, 3), acc, false);
  acc = __builtin_amdgcn_fdot2(__builtin_shufflevector(a, a, 4, 5),
                               __builtin_shufflevector(b, b, 4, 5), acc, false);
  acc = __builtin_amdgcn_fdot2(__builtin_shufflevector(a, a, 6, 7),
                               __builtin_shufflevector(b, b, 6, 7), acc, false);
#else
#pragma unroll
  for (int i = 0; i < 8; ++i) acc += (float)a[i] * (float)b[i];
#endif
  return acc;
}

// ---------------- weight f32 -> f16 cast ----------------
__global__ __launch_bounds__(256) void wcast_f16_kernel(
    const float* __restrict__ src, _Float16* __restrict__ dst) {
  const size_t e = ((size_t)blockIdx.x * 256 + threadIdx.x) * 4;
  const float4 v = *(const float4*)(src + e);
  half4 h;
  h.x = (_Float16)v.x; h.y = (_Float16)v.y; h.z = (_Float16)v.z; h.w = (_Float16)v.w;
  *(half4*)(dst + e) = h;
}

// ---------------- fused token-shift mix: x -> xr,xk,xv,xg (f16), x read once ----------------
__global__ __launch_bounds__(256) void mix4_kernel(
    const float* __restrict__ x, const float* __restrict__ state,
    const float* __restrict__ tmr, const float* __restrict__ tmk,
    const float* __restrict__ tmv, const float* __restrict__ tmg,
    _Float16* __restrict__ xr, _Float16* __restrict__ xk,
    _Float16* __restrict__ xv, _Float16* __restrict__ xg) {
  const size_t e = ((size_t)blockIdx.x * 256 + threadIdx.x) * 4;
  const int c = (int)(e & (Cn - 1));
  const int t = (int)((e >> 11) & (Tn - 1));
  float4 xv_ = *(const float4*)(x + e);
  float4 xx  = (t == 0) ? *(const float4*)(state + c) : *(const float4*)(x + e - Cn);
  float4 dx; dx.x = xv_.x - xx.x; dx.y = xv_.y - xx.y; dx.z = xv_.z - xx.z; dx.w = xv_.w - xx.w;
  const float* tms[4] = {tmr, tmk, tmv, tmg};
  _Float16* dsts[4] = {xr, xk, xv, xg};
#pragma unroll
  for (int s = 0; s < 4; ++s) {
    float4 m = *(const float4*)(tms[s] + c);
    half4 o;
    o.x = (_Float16)(xx.x + dx.x * m.x);
    o.y = (_Float16)(xx.y + dx.y * m.y);
    o.z = (_Float16)(xx.z + dx.z * m.z);
    o.w = (_Float16)(xx.w + dx.w * m.w);
    *(half4*)(dsts[s] + e) = o;
  }
}

// ---------------- f16 GEMM, 256x256 tile, BK=64, 8 waves, counted-vmcnt pipeline ----------
template <int OUT_F16>
__global__ __launch_bounds__(512, 2) void gemm256_kernel(
    const _Float16* __restrict__ A, const _Float16* __restrict__ W,
    void* __restrict__ Ov) {
  __shared__ _Float16 As[2][256 * 64];   // 32 KB per buffer
  __shared__ _Float16 Bs[2][256 * 64];   // total 128 KB
  const int tid = threadIdx.x;
  const int wid = tid >> 6, ln = tid & 63;
  const int wm = wid >> 2, wn = wid & 3;          // 2 x 4 wave grid; wave owns 128x64 of C
  const int m16 = ln & 15, qd = ln >> 4;

  const int mtile = blockIdx.y, ntile = blockIdx.x;
  const _Float16* Ab = A + (size_t)mtile * 256 * Cn;
  const _Float16* Wb = W + (size_t)ntile * 256 * Cn;

  const _Float16* gA[4]; const _Float16* gB[4];
  int lof[4];
#pragma unroll
  for (int i = 0; i < 4; ++i) {
    int r = ((wid * 4 + i) << 3) + (ln >> 3);
    int q = (ln & 7) ^ (r & 7);
    gA[i] = Ab + (size_t)r * Cn + (q << 3);
    gB[i] = Wb + (size_t)r * Cn + (q << 3);
    lof[i] = ((wid * 4 + i) << 10);               // wave-uniform LDS byte base
  }
  int aob[2], bob[2];
#pragma unroll
  for (int h = 0; h < 2; ++h) {
    int sl = ((h << 2) + qd) ^ (m16 & 7);
    aob[h] = (wm * 128 + m16) * 128 + sl * 16;    // + fr*2048 per frag row
    bob[h] = (wn * 64 + m16) * 128 + sl * 16;     // + nf*2048 per frag col
  }

  f32x4 acc[8][4];
#pragma unroll
  for (int i = 0; i < 8; ++i)
#pragma unroll
    for (int j = 0; j < 4; ++j) acc[i][j] = 0.f;

#pragma unroll
  for (int i = 0; i < 4; ++i) {
    __builtin_amdgcn_global_load_lds(
        (const __attribute__((address_space(1))) void*)(gA[i]),
        (__attribute__((address_space(3))) void*)((char*)&As[0][0] + lof[i]), 16, 0, 0);
    __builtin_amdgcn_global_load_lds(
        (const __attribute__((address_space(1))) void*)(gB[i]),
        (__attribute__((address_space(3))) void*)((char*)&Bs[0][0] + lof[i]), 16, 0, 0);
  }

  const int NT = Cn / 64;
  for (int t = 0; t < NT; ++t) {
    const int b = t & 1;
    if (t + 1 < NT) {
      const int k0 = (t + 1) << 6;
#pragma unroll
      for (int i = 0; i < 4; ++i) {
        __builtin_amdgcn_global_load_lds(
            (const __attribute__((address_space(1))) void*)(gA[i] + k0),
            (__attribute__((address_space(3))) void*)((char*)&As[b ^ 1][0] + lof[i]), 16, 0, 0);
        __builtin_amdgcn_global_load_lds(
            (const __attribute__((address_space(1))) void*)(gB[i] + k0),
            (__attribute__((address_space(3))) void*)((char*)&Bs[b ^ 1][0] + lof[i]), 16, 0, 0);
      }
      asm volatile("s_waitcnt vmcnt(8)" ::: "memory");   // tile-t loads done; 8 stay in flight
    } else {
      asm volatile("s_waitcnt vmcnt(0)" ::: "memory");
    }
    __builtin_amdgcn_s_barrier();

    const char* Abase = (const char*)&As[b][0];
    const char* Bbase = (const char*)&Bs[b][0];
    half8 bfr[4][2];
#pragma unroll
    for (int nf = 0; nf < 4; ++nf)
#pragma unroll
      for (int h = 0; h < 2; ++h)
        bfr[nf][h] = *(const half8*)(Bbase + nf * 2048 + bob[h]);
#pragma unroll
    for (int p = 0; p < 4; ++p) {
      half8 af[2][2];
#pragma unroll
      for (int sub = 0; sub < 2; ++sub)
#pragma unroll
        for (int h = 0; h < 2; ++h)
          af[sub][h] = *(const half8*)(Abase + (p * 2 + sub) * 2048 + aob[h]);
      __builtin_amdgcn_s_setprio(1);
#pragma unroll
      for (int sub = 0; sub < 2; ++sub)
#pragma unroll
        for (int nf = 0; nf < 4; ++nf) {
          acc[p * 2 + sub][nf] =
              __builtin_amdgcn_mfma_f32_16x16x32_f16(af[sub][0], bfr[nf][0], acc[p * 2 + sub][nf], 0, 0, 0);
          acc[p * 2 + sub][nf] =
              __builtin_amdgcn_mfma_f32_16x16x32_f16(af[sub][1], bfr[nf][1], acc[p * 2 + sub][nf], 0, 0, 0);
        }
      __builtin_amdgcn_s_setprio(0);
    }
    __builtin_amdgcn_s_barrier();   // all reads of buf b done before next iter stages into it
  }

  const size_t obase = (size_t)mtile * 256 * Cn + (size_t)ntile * 256;
#pragma unroll
  for (int fr = 0; fr < 8; ++fr) {
#pragma unroll
    for (int nf = 0; nf < 4; ++nf) {
      int col  = wn * 64 + nf * 16 + m16;
      int row0 = wm * 128 + fr * 16 + (qd << 2);
      f32x4 cv = acc[fr][nf];
      if constexpr (OUT_F16) {
        _Float16* Ob = (_Float16*)Ov + obase;
#pragma unroll
        for (int rg = 0; rg < 4; ++rg)
          Ob[(size_t)(row0 + rg) * Cn + col] = (_Float16)cv[rg];
      } else {
        float* Ob = (float*)Ov + obase;
#pragma unroll
        for (int rg = 0; rg < 4; ++rg)
          Ob[(size_t)(row0 + rg) * Cn + col] = cv[rg];
      }
    }
  }
}

// ---------------- scan pass 1: per-segment state sums ----------------
__global__ __launch_bounds__(256) void seg_sum_kernel(
    const _Float16* __restrict__ kA, const _Float16* __restrict__ vA,
    const float* __restrict__ td, float* __restrict__ segsum) {
  __shared__ float sK[32][68];    // k * w^(T-1-t)
  __shared__ float sV[32][68];
  __shared__ float sEw[64];
  __shared__ float sEwMin;
  const int tid = threadIdx.x;
  const int bh = blockIdx.x;
  const int seg = SEGS - 1 - blockIdx.y;
  const int b = bh >> 5, h = bh & 31;
  const size_t colbase = (size_t)b * Tn * Cn + h * 64;
  const _Float16* kG = kA + colbase;
  const _Float16* vG = vA + colbase;

  if (tid < 64) sEw[tid] = __expf(td[h * 64 + tid]);
  __syncthreads();
  if (tid == 0) {
    float mn = sEw[0];
    for (int i = 1; i < 64; ++i) mn = fminf(mn, sEw[i]);
    sEwMin = mn;
  }
  __syncthreads();

  const int uk0 = (tid >> 4) << 2;      // S k base
  const int uj0 = (tid & 15) << 2;      // S j base
  float su[16];
#pragma unroll
  for (int i = 0; i < 16; ++i) su[i] = 0.f;

  const int c0 = seg * (64 / SEGS), c1 = c0 + (64 / SEGS);
  for (int c = c0; c < c1; ++c) {
    const int tb = c << 5;
    if ((float)(Tn - 32 - tb) * sEwMin >= ZTHR) continue;   // whole chunk underflows
#pragma unroll
    for (int rep = 0; rep < 2; ++rep) {
      int f4 = tid + (rep << 8);
      int row = f4 >> 4;
      int col = (f4 & 15) << 2;
      int t = tb + row;
      size_t off = (size_t)t * Cn + col;
      half4 ku = *(const half4*)(kG + off);
      half4 vu = *(const half4*)(vG + off);
      float4 vf; vf.x = (float)vu.x; vf.y = (float)vu.y; vf.z = (float)vu.z; vf.w = (float)vu.w;
      *(float4*)&sV[row][col] = vf;
      float e = (float)(Tn - 1 - t);
      float4 kw;
      kw.x = (float)ku.x * __expf(-e * sEw[col + 0]);
      kw.y = (float)ku.y * __expf(-e * sEw[col + 1]);
      kw.z = (float)ku.z * __expf(-e * sEw[col + 2]);
      kw.w = (float)ku.w * __expf(-e * sEw[col + 3]);
      *(float4*)&sK[row][col] = kw;
    }
    __syncthreads();
    for (int q = 0; q < 32; ++q) {
      float4 kq = *(const float4*)&sK[q][uk0];
      float4 vq = *(const float4*)&sV[q][uj0];
      su[0]  += kq.x * vq.x; su[1]  += kq.x * vq.y; su[2]  += kq.x * vq.z; su[3]  += kq.x * vq.w;
      su[4]  += kq.y * vq.x; su[5]  += kq.y * vq.y; su[6]  += kq.y * vq.z; su[7]  += kq.y * vq.w;
      su[8]  += kq.z * vq.x; su[9]  += kq.z * vq.y; su[10] += kq.z * vq.z; su[11] += kq.z * vq.w;
      su[12] += kq.w * vq.x; su[13] += kq.w * vq.y; su[14] += kq.w * vq.z; su[15] += kq.w * vq.w;
    }
    __syncthreads();
  }
  float* dst = segsum + ((size_t)bh * SEGS + seg) * 4096;
#pragma unroll
  for (int i = 0; i < 4; ++i) {
    float4 s; s.x = su[i * 4 + 0]; s.y = su[i * 4 + 1]; s.z = su[i * 4 + 2]; s.w = su[i * 4 + 3];
    *(float4*)(dst + (uk0 + i) * 64 + uj0) = s;
  }
}

// ---------------- scan pass 2: f16-LDS, swizzled, fdot2 att ----------------
// grid (128, SEGS): x = bh, y -> seg (reversed, heavy-first).
// skipc <=> whole chunk's kw underflows f32; snz => !skipc (monotone); active guards RW@S0.
__global__ __launch_bounds__(256) void scan_kernel(
    const _Float16* __restrict__ rA, const _Float16* __restrict__ kA,
    const _Float16* __restrict__ vA, const _Float16* __restrict__ gA,
    const float* __restrict__ wkvst, const float* __restrict__ td,
    const float* __restrict__ faaaa, const float* __restrict__ lnw,
    const float* __restrict__ lnb, const float* __restrict__ segsum,
    _Float16* __restrict__ A2) {
  __shared__ __align__(16) _Float16 sR[32][72];
  __shared__ __align__(16) _Float16 sK[32][72];    // k * w^(T-1-t), f16 (flush < 6e-8 ~ ref underflow)
  __shared__ __align__(16) _Float16 sV[32][72];
  __shared__ __align__(16) _Float16 sRW[32][72];   // r * w^t (active only)
  __shared__ __align__(16) _Float16 sS0[64][72];   // wkvstate, f16
  __shared__ float sS[64][68];                     // running state, f32
  __shared__ float sAtt[32][36];
  __shared__ float sEw[64];
  __shared__ float sU[64];
  __shared__ float sDotP[32][8];
  __shared__ float sRedM[32][8];
  __shared__ float sRedQ[32][8];
  __shared__ float sMV[32][2];
  __shared__ float sEwMin;
  const int tid = threadIdx.x;
  const int bh = blockIdx.x;
  const int seg = SEGS - 1 - blockIdx.y;
  const int b = bh >> 5, h = bh & 31;
  const size_t colbase = (size_t)b * Tn * Cn + h * 64;
  const _Float16* rG = rA + colbase;
  const _Float16* kG = kA + colbase;
  const _Float16* vG = vA + colbase;
  const _Float16* gG = gA + colbase;
  _Float16* outG = A2 + colbase;

  if (tid < 64) {
    sEw[tid] = __expf(td[h * 64 + tid]);
    sU[tid]  = faaaa[h * 64 + tid];
  }
  // ---- init sS = prefix of segment sums (f32); stage S0 (f16, swizzled) ----
  {
    float4 acc4[4];
#pragma unroll
    for (int j = 0; j < 4; ++j) { acc4[j].x = 0.f; acc4[j].y = 0.f; acc4[j].z = 0.f; acc4[j].w = 0.f; }
    for (int sp = 0; sp < seg; ++sp) {
      const float* basep = segsum + ((size_t)bh * SEGS + sp) * 4096;
#pragma unroll
      for (int j = 0; j < 4; ++j) {
        int f4 = tid + j * 256;
        int row = f4 >> 4, c4 = (f4 & 15) << 2;
        float4 m = *(const float4*)(basep + row * 64 + c4);
        acc4[j].x += m.x; acc4[j].y += m.y; acc4[j].z += m.z; acc4[j].w += m.w;
      }
    }
#pragma unroll
    for (int j = 0; j < 4; ++j) {
      int f4 = tid + j * 256;
      int row = f4 >> 4, c4 = (f4 & 15) << 2;
      *(float4*)&sS[row][c4] = acc4[j];
    }
    // S0: row = tid>>2, 16 cols starting (tid&3)*16; two swizzled half8 stores
    int row = tid >> 2, c0 = (tid & 3) << 4;
    const float* sp = wkvst + (size_t)h * 4096 + row * 64 + c0;
    float4 f0 = *(const float4*)(sp);
    float4 f1 = *(const float4*)(sp + 4);
    float4 f2 = *(const float4*)(sp + 8);
    float4 f3 = *(const float4*)(sp + 12);
    half8 h0, h1;
    h0[0] = (_Float16)f0.x; h0[1] = (_Float16)f0.y; h0[2] = (_Float16)f0.z; h0[3] = (_Float16)f0.w;
    h0[4] = (_Float16)f1.x; h0[5] = (_Float16)f1.y; h0[6] = (_Float16)f1.z; h0[7] = (_Float16)f1.w;
    h1[0] = (_Float16)f2.x; h1[1] = (_Float16)f2.y; h1[2] = (_Float16)f2.z; h1[3] = (_Float16)f2.w;
    h1[4] = (_Float16)f3.x; h1[5] = (_Float16)f3.y; h1[6] = (_Float16)f3.z; h1[7] = (_Float16)f3.w;
    *(half8*)&sS0[row][SWZ(row, c0)] = h0;
    *(half8*)&sS0[row][SWZ(row, c0 + 8)] = h1;
  }
  __syncthreads();
  if (tid == 0) {
    float mn = sEw[0];
    for (int i = 1; i < 64; ++i) mn = fminf(mn, sEw[i]);
    sEwMin = mn;
  }
  __syncthreads();

  const int ap  = tid >> 3;             // att/out row (0..31)
  const int aq0 = (tid & 7) << 2;       // att col base
  const int oj0 = (tid & 7) << 3;       // out col base (8 cols)
  const int uk0 = (tid >> 4) << 2;      // S-update k base
  const int uj0 = (tid & 15) << 2;      // S-update j base
  const int srow = tid >> 3;            // staging row (== ap)
  const int scol = (tid & 7) << 3;      // staging col (8 cols, 128B contiguous per row)
  float lw[8], lb[8];
#pragma unroll
  for (int i = 0; i < 8; ++i) { lw[i] = lnw[h * 64 + oj0 + i]; lb[i] = lnb[h * 64 + oj0 + i]; }

  bool snz = (seg > 0) && ((float)(Tn - seg * 256) * sEwMin < ZTHR);

  const int c0 = seg * (64 / SEGS), c1 = c0 + (64 / SEGS);
  for (int c = c0; c < c1; ++c) {
    const int tb = c << 5;
    const bool skipc  = ((float)(Tn - 32 - tb) * sEwMin) >= ZTHR;  // kw == 0 whole chunk
    const bool active = ((float)tb * sEwMin) < 88.f;               // w^t nonzero somewhere
    // ---- stage r, k*wback, v (f16 LDS, swizzled) + u-dot partials + r*w^t ----
    {
      int t = tb + srow;
      size_t off = (size_t)t * Cn + scol;
      half8 ru = *(const half8*)(rG + off);
      half8 ku = *(const half8*)(kG + off);
      half8 vu = *(const half8*)(vG + off);
      *(half8*)&sV[srow][SWZ(srow, scol)] = vu;
      float dp = 0.f;
#pragma unroll
      for (int i = 0; i < 8; ++i) dp += (float)ku[i] * (float)ru[i] * sU[scol + i];
      sDotP[srow][tid & 7] = dp;
      if (!skipc) {
        *(half8*)&sR[srow][SWZ(srow, scol)] = ru;
        float e = (float)(Tn - 1 - t);
        half8 kwh;
#pragma unroll
        for (int i = 0; i < 8; ++i)
          kwh[i] = (_Float16)((float)ku[i] * __expf(-e * sEw[scol + i]));
        *(half8*)&sK[srow][SWZ(srow, scol)] = kwh;
      }
      if (active) {
        float tt = (float)t;
        half8 rwh;
#pragma unroll
        for (int i = 0; i < 8; ++i)
          rwh[i] = (_Float16)((float)ru[i] * __expf(-tt * sEw[scol + i]));
        *(half8*)&sRW[srow][SWZ(srow, scol)] = rwh;
      }
    }
    __syncthreads();
    // ---- att[p][q] = r_p . kw_q via fdot2, strict mask q < p ----
    if (!skipc) {
      float a4[4] = {0.f, 0.f, 0.f, 0.f};
      for (int k = 0; k < 64; k += 8) {
        half8 rv = *(const half8*)&sR[ap][SWZ(ap, k)];
#pragma unroll
        for (int qq = 0; qq < 4; ++qq) {
          int row = aq0 + qq;
          half8 kv = *(const half8*)&sK[row][SWZ(row, k)];
          a4[qq] = dot8(rv, kv, a4[qq]);
        }
      }
#pragma unroll
      for (int qq = 0; qq < 4; ++qq)
        sAtt[ap][aq0 + qq] = ((aq0 + qq) < ap) ? a4[qq] : 0.f;
      __syncthreads();
    }
    // ---- out = [att@V] + [R@S] + [RW@S0] + dot*v; bf16-round; GN partials ----
    float y[8];
    {
      float o[8];
#pragma unroll
      for (int i = 0; i < 8; ++i) o[i] = 0.f;
      if (!skipc) {
        for (int q = 0; q < 32; ++q) {
          float aw = sAtt[ap][q];
          half8 vv = *(const half8*)&sV[q][SWZ(q, oj0)];
#pragma unroll
          for (int i = 0; i < 8; ++i) o[i] += aw * (float)vv[i];
        }
      }
      if (snz) {
        for (int k8 = 0; k8 < 64; k8 += 8) {
          half8 rv = *(const half8*)&sR[ap][SWZ(ap, k8)];
#pragma unroll
          for (int kk = 0; kk < 8; ++kk) {
            float rw = (float)rv[kk];
            const float* srow_ = &sS[k8 + kk][oj0];
            float4 s0 = *(const float4*)(srow_);
            float4 s1 = *(const float4*)(srow_ + 4);
            o[0] += rw * s0.x; o[1] += rw * s0.y; o[2] += rw * s0.z; o[3] += rw * s0.w;
            o[4] += rw * s1.x; o[5] += rw * s1.y; o[6] += rw * s1.z; o[7] += rw * s1.w;
          }
        }
      }
      if (active) {
        for (int k8 = 0; k8 < 64; k8 += 8) {
          half8 rv = *(const half8*)&sRW[ap][SWZ(ap, k8)];
#pragma unroll
          for (int kk = 0; kk < 8; ++kk) {
            float rw = (float)rv[kk];
            int k = k8 + kk;
            half8 s08 = *(const half8*)&sS0[k][SWZ(k, oj0)];
#pragma unroll
            for (int i = 0; i < 8; ++i) o[i] += rw * (float)s08[i];
          }
        }
      }
      float dot = 0.f;
#pragma unroll
      for (int s = 0; s < 8; ++s) dot += sDotP[ap][s];
      half8 vme = *(const half8*)&sV[ap][SWZ(ap, oj0)];
#pragma unroll
      for (int i = 0; i < 8; ++i) o[i] += dot * (float)vme[i];
      float sm = 0.f, sq = 0.f;
#pragma unroll
      for (int i = 0; i < 8; ++i) {
        y[i] = bf2f(f2bf(o[i]));
        sm += y[i]; sq += y[i] * y[i];
      }
      sRedM[ap][tid & 7] = sm; sRedQ[ap][tid & 7] = sq;
    }
    __syncthreads();
    if ((tid & 7) == 0) {
      float sm = 0.f, sq = 0.f;
#pragma unroll
      for (int i = 0; i < 8; ++i) { sm += sRedM[ap][i]; sq += sRedQ[ap][i]; }
      float mu = sm * (1.f / 64.f);
      float var = sq * (1.f / 64.f) - mu * mu;
      sMV[ap][0] = mu; sMV[ap][1] = rsqrtf(var + EPSV);
    }
    __syncthreads();
    {
      float mu = sMV[ap][0], rs = sMV[ap][1];
      int t = tb + ap;
      size_t off = (size_t)t * Cn + oj0;
      half8 g8 = *(const half8*)(gG + off);
      half8 o8;
#pragma unroll
      for (int i = 0; i < 8; ++i) {
        float gv = (float)g8[i];
        float yn = (y[i] - mu) * rs * lw[i] + lb[i];
        float gs = gv / (1.f + __expf(-gv));
        o8[i] = (_Float16)(yn * gs);
      }
      *(half8*)(outG + off) = o8;
    }
    // ---- S += Kw^T V (f32 acc from f16 operands) ----
    if (!skipc) {
      float su[16];
#pragma unroll
      for (int i = 0; i < 4; ++i) {
        float4 s = *(const float4*)&sS[uk0 + i][uj0];
        su[i * 4 + 0] = s.x; su[i * 4 + 1] = s.y; su[i * 4 + 2] = s.z; su[i * 4 + 3] = s.w;
      }
      for (int q = 0; q < 32; ++q) {
        half4 kq4 = *(const half4*)&sK[q][SWZ(q, uk0)];
        half4 vq4 = *(const half4*)&sV[q][SWZ(q, uj0)];
        float kx = (float)kq4.x, ky = (float)kq4.y, kz = (float)kq4.z, kw_ = (float)kq4.w;
        float vx = (float)vq4.x, vy = (float)vq4.y, vz = (float)vq4.z, vw = (float)vq4.w;
        su[0]  += kx * vx; su[1]  += kx * vy; su[2]  += kx * vz; su[3]  += kx * vw;
        su[4]  += ky * vx; su[5]  += ky * vy; su[6]  += ky * vz; su[7]  += ky * vw;
        su[8]  += kz * vx; su[9]  += kz * vy; su[10] += kz * vz; su[11] += kz * vw;
        su[12] += kw_ * vx; su[13] += kw_ * vy; su[14] += kw_ * vz; su[15] += kw_ * vw;
      }
#pragma unroll
      for (int i = 0; i < 4; ++i) {
        float4 s; s.x = su[i * 4 + 0]; s.y = su[i * 4 + 1]; s.z = su[i * 4 + 2]; s.w = su[i * 4 + 3];
        *(float4*)&sS[uk0 + i][uj0] = s;
      }
      snz = true;
      __syncthreads();
    }
  }
}

// ---------------- launcher ----------------
extern "C" void kernel_launch(void* const* d_in, const int* in_sizes, int n_in,
                              void* d_out, int out_size, void* d_ws, size_t ws_size,
                              hipStream_t stream) {
  const float* x     = (const float*)d_in[0];
  const float* state = (const float*)d_in[1];
  const float* wkvst = (const float*)d_in[2];
  const float* tmk   = (const float*)d_in[3];
  const float* tmv   = (const float*)d_in[4];
  const float* tmr   = (const float*)d_in[5];
  const float* tmg   = (const float*)d_in[6];
  const float* td    = (const float*)d_in[7];
  const float* faaaa = (const float*)d_in[8];
  const float* w_r   = (const float*)d_in[9];
  const float* w_k   = (const float*)d_in[10];
  const float* w_v   = (const float*)d_in[11];
  const float* w_g   = (const float*)d_in[12];
  const float* w_o   = (const float*)d_in[13];
  const float* ln_w  = (const float*)d_in[14];
  const float* ln_b  = (const float*)d_in[15];
  float* out = (float*)d_out;
  char* ws = (char*)d_ws;

  // ws layout (bytes), peak 201,326,592 (same as proven layout):
  //  [0, 8.4M)       weight f16 (reused per GEMM)
  //  M0..M3          mix outputs xr,xk,xv,xg (33.55M each); projections recycle dead slots:
  //                  R->Rbuf, K->M0, V->M1, G->M2, A2->M3
  //  [184.5M,201.3M) segsum f32
  const size_t SLOT = 33554432;
  _Float16* wh   = (_Float16*)(ws);
  _Float16* M0   = (_Float16*)(ws + 16777216);
  _Float16* M1   = (_Float16*)(ws + 16777216 + SLOT);
  _Float16* M2   = (_Float16*)(ws + 16777216 + 2 * SLOT);
  _Float16* M3   = (_Float16*)(ws + 16777216 + 3 * SLOT);
  _Float16* Rbuf = (_Float16*)(ws + 16777216 + 4 * SLOT);
  float* segsum  = (float*)(ws + 184549376);

  // fused mix: x -> xr(M0), xk(M1), xv(M2), xg(M3)
  mix4_kernel<<<dim3(16384), 256, 0, stream>>>(x, state, tmr, tmk, tmv, tmg, M0, M1, M2, M3);

  const float* wsrc[4] = {w_r, w_k, w_v, w_g};
  const _Float16* asrc[4] = {M0, M1, M2, M3};
  _Float16* pdst[4] = {Rbuf, M0, M1, M2};   // each GEMM writes into a slot already consumed

  for (int s = 0; s < 4; ++s) {
    wcast_f16_kernel<<<dim3(4096), 256, 0, stream>>>(wsrc[s], wh);
    gemm256_kernel<1><<<dim3(Cn / 256, Mn / 256), 512, 0, stream>>>(asrc[s], wh, pdst[s]);
  }
  _Float16* R = Rbuf;
  _Float16* K = M0;
  _Float16* V = M1;
  _Float16* G = M2;
  _Float16* A2 = M3;   // xg dead after G-GEMM

  seg_sum_kernel<<<dim3(128, SEGS), 256, 0, stream>>>(K, V, td, segsum);
  scan_kernel<<<dim3(128, SEGS), 256, 0, stream>>>(R, K, V, G, wkvst, td, faaaa,
                                                   ln_w, ln_b, segsum, A2);

  wcast_f16_kernel<<<dim3(4096), 256, 0, stream>>>(w_o, wh);
  gemm256_kernel<0><<<dim3(Cn / 256, Mn / 256), 512, 0, stream>>>(A2, wh, out);

  (void)in_sizes; (void)n_in; (void)out_size; (void)ws_size;
}